// Round 3
// baseline (4626.679 us; speedup 1.0000x reference)
//
#include <hip/hip_runtime.h>
#include <hip/hip_bf16.h>
#include <stdint.h>

using bf16 = __hip_bfloat16;

#define TOKENS 4096
#define HID    2048
#define VD     3072
#define NH     6
#define HD     512
#define NC     32
#define CHUNK  64

// ---------------------------------------------------------------- naive tiled f32 GEMM
// C[m][n] = sum_k A[m][k] * B[k][colmap(n)]
// mode 0: colmap(n) = n ; mode 1: colmap(n) = (n>>8)*512 + (n&255)*2  (even-column gather)
__global__ __launch_bounds__(256) void k_ngemm(const float* __restrict__ A,
                                               const float* __restrict__ B,
                                               float* __restrict__ C,
                                               int M, int N, int K, int ldb,
                                               int mode) {
    __shared__ float sA[16][64];      // [k][m]
    __shared__ float sB[16][64 + 1];  // [k][n]
    const int tid = threadIdx.x;
    const int tx = tid & 15;          // n-group
    const int ty = tid >> 4;          // m-group
    const int bm = blockIdx.y * 64;
    const int bn = blockIdx.x * 64;
    float acc[4][4] = {};

    for (int kt = 0; kt < K; kt += 16) {
#pragma unroll
        for (int i = 0; i < 4; ++i) {          // A tile: 64 rows x 16 k
            int row = (tid >> 4) + i * 16;
            int kk  = tid & 15;
            sA[kk][row] = A[(size_t)(bm + row) * K + kt + kk];
        }
#pragma unroll
        for (int i = 0; i < 4; ++i) {          // B tile: 16 k x 64 n
            int kk = (tid >> 6) + i * 4;
            int n  = tid & 63;
            int col = bn + n;
            int bcol = (mode == 1) ? ((col >> 8) * 512 + (col & 255) * 2) : col;
            sB[kk][n] = B[(size_t)(kt + kk) * ldb + bcol];
        }
        __syncthreads();
#pragma unroll
        for (int kk = 0; kk < 16; ++kk) {
            float a[4], b[4];
#pragma unroll
            for (int i = 0; i < 4; ++i) a[i] = sA[kk][ty * 4 + i];
#pragma unroll
            for (int j = 0; j < 4; ++j) b[j] = sB[kk][tx * 4 + j];
#pragma unroll
            for (int i = 0; i < 4; ++i)
#pragma unroll
                for (int j = 0; j < 4; ++j) acc[i][j] = fmaf(a[i], b[j], acc[i][j]);
        }
        __syncthreads();
    }
#pragma unroll
    for (int i = 0; i < 4; ++i) {
        int r = bm + ty * 4 + i;
#pragma unroll
        for (int j = 0; j < 4; ++j) {
            int c = bn + tx * 4 + j;
            C[(size_t)r * N + c] = acc[i][j];
        }
    }
}

// ---------------------------------------------------------------- alpha/beta (tiny GEMM + sigmoid)
__global__ __launch_bounds__(256) void k_ab(const float* __restrict__ hs, const float* __restrict__ Wa,
                                            const float* __restrict__ Wb,
                                            float* __restrict__ alpha, float* __restrict__ beta) {
    const int tok = blockIdx.x;
    const int tid = threadIdx.x;
    float part[12];
#pragma unroll
    for (int j = 0; j < 12; ++j) part[j] = 0.f;
    const float* hrow = hs + (size_t)tok * HID;
    for (int i = 0; i < 8; ++i) {
        int k = i * 256 + tid;
        float x = hrow[k];
        const float* wa = Wa + k * NH;
        const float* wb = Wb + k * NH;
#pragma unroll
        for (int j = 0; j < NH; ++j) {
            part[j]     = fmaf(x, wa[j], part[j]);
            part[6 + j] = fmaf(x, wb[j], part[6 + j]);
        }
    }
    __shared__ float red[12][4];
    const int lane = tid & 63, wv = tid >> 6;
#pragma unroll
    for (int j = 0; j < 12; ++j) {
        float s = part[j];
        for (int off = 32; off; off >>= 1) s += __shfl_down(s, off);
        if (lane == 0) red[j][wv] = s;
    }
    __syncthreads();
    if (tid < 12) {
        float s = red[tid][0] + red[tid][1] + red[tid][2] + red[tid][3];
        float v = 1.f / (1.f + expf(-s));
        if (tid < 6) alpha[(size_t)tok * NH + tid] = v;
        else         beta [(size_t)tok * NH + tid - 6] = v;
    }
}

// ---------------------------------------------------------------- conv + phase + rotate + local chunk scan
__global__ __launch_bounds__(256) void k_scan1f(const float* __restrict__ qe,
                                                const float* __restrict__ ke,
                                                const float* __restrict__ vv,
                                                const float* __restrict__ alpha,
                                                const float* __restrict__ beta,
                                                const float* __restrict__ cq,
                                                const float* __restrict__ ck,
                                                const float* __restrict__ cvw,
                                                float* __restrict__ U, float* __restrict__ pp) {
    const int bx = blockIdx.x;
    const int c  = bx & (NC - 1);
    const int h  = (bx >> 5) % NH;
    const int b  = bx / (NC * NH);
    const int p  = threadIdx.x;
    const int t0 = c * CHUNK;
    const int ch2 = h * HD + 2 * p;
    const float wq0 = cq[ch2 * 4 + 0], wq1 = cq[ch2 * 4 + 1], wq2 = cq[ch2 * 4 + 2], wq3 = cq[ch2 * 4 + 3];
    const float wk0 = ck[ch2 * 4 + 0], wk1 = ck[ch2 * 4 + 1], wk2 = ck[ch2 * 4 + 2], wk3 = ck[ch2 * 4 + 3];
    const float wa0 = cvw[ch2 * 4 + 0], wa1 = cvw[ch2 * 4 + 1], wa2 = cvw[ch2 * 4 + 2], wa3 = cvw[ch2 * 4 + 3];
    const float wb0 = cvw[(ch2 + 1) * 4 + 0], wb1 = cvw[(ch2 + 1) * 4 + 1],
                wb2 = cvw[(ch2 + 1) * 4 + 2], wb3 = cvw[(ch2 + 1) * 4 + 3];
    const float invf = exp2f(-13.287712379549449f * ((float)p * (1.0f / 256.0f)));
    const int qoff = h * 256 + p;       // into width-1536 qe/ke rows
    const int voff = h * HD + 2 * p;    // into width-3072 v rows

    float xq[3], xk[3], xv0[3], xv1[3];
#pragma unroll
    for (int i = 0; i < 3; ++i) {
        int t = t0 - 3 + i;
        if (t >= 0) {
            size_t tok = (size_t)b * 2048 + t;
            xq[i] = qe[tok * 1536 + qoff];
            xk[i] = ke[tok * 1536 + qoff];
            float2 v2 = *(const float2*)&vv[tok * (size_t)VD + voff];
            xv0[i] = v2.x;
            xv1[i] = v2.y;
        } else { xq[i] = xk[i] = xv0[i] = xv1[i] = 0.f; }
    }

    float u0 = 0.f, u1 = 0.f, ap = 1.f;
    for (int t = t0; t < t0 + CHUNK; ++t) {
        const size_t tok = (size_t)b * 2048 + t;
        float nq = qe[tok * 1536 + qoff];
        float nk = ke[tok * 1536 + qoff];
        float2 v2 = *(const float2*)&vv[tok * (size_t)VD + voff];
        float nv0 = v2.x, nv1 = v2.y;
        float yq  = wq3 * nq  + wq2 * xq[2]  + wq1 * xq[1]  + wq0 * xq[0];
        float yk  = wk3 * nk  + wk2 * xk[2]  + wk1 * xk[1]  + wk0 * xk[0];
        float yv0 = wa3 * nv0 + wa2 * xv0[2] + wa1 * xv0[1] + wa0 * xv0[0];
        float yv1 = wb3 * nv1 + wb2 * xv1[2] + wb1 * xv1[1] + wb0 * xv1[0];
        xq[0] = xq[1]; xq[1] = xq[2]; xq[2] = nq;
        xk[0] = xk[1]; xk[1] = xk[2]; xk[2] = nk;
        xv0[0] = xv0[1]; xv0[1] = xv0[2]; xv0[2] = nv0;
        xv1[0] = xv1[1]; xv1[1] = xv1[2]; xv1[2] = nv1;
        float theta = yq * invf, psi = yk * invf;
        float d = psi - theta, sn, cs;
        __sincosf(d, &sn, &cs);
        float w0 = yv0 * cs - yv1 * sn;
        float w1 = yv1 * cs + yv0 * sn;
        float a  = alpha[tok * NH + h];
        float bb = beta [tok * NH + h];
        u0 = fmaf(a, u0, bb * w0);
        u1 = fmaf(a, u1, bb * w1);
        ap *= a;
        *(float2*)&U[tok * (size_t)VD + h * HD + 2 * p] = float2{u0, u1};
        if (p == 0) pp[tok * NH + h] = ap;
    }
}

// ---------------------------------------------------------------- cross-chunk carry (sequential over 32 chunks)
__global__ void k_carry(const float* __restrict__ U, const float* __restrict__ pp,
                        float* __restrict__ carry) {
    const int bh = blockIdx.x;              // 0..11 = b*NH+h
    const int b = bh / NH, h = bh % NH;
    const int tid = threadIdx.x;
    for (int half = 0; half < 2; ++half) {
        const int d = tid + half * 256;
        float s = 0.f;
        for (int c = 0; c < NC; ++c) {
            carry[((size_t)bh * NC + c) * HD + d] = s;
            int tend = c * CHUNK + CHUNK - 1;
            size_t tok = (size_t)b * 2048 + tend;
            s = U[tok * (size_t)VD + h * HD + d] + pp[tok * NH + h] * s;
        }
    }
}

// ---------------------------------------------------------------- carry fix + RMS + SiLU gate
__global__ __launch_bounds__(256) void k_pass3f(const float* __restrict__ U, const float* __restrict__ pp,
                                                const float* __restrict__ carry, const float* __restrict__ g,
                                                const float* __restrict__ rms_w, float* __restrict__ O) {
    const int bx = blockIdx.x;              // tok*NH + h
    const int h = bx % NH;
    const size_t tok = bx / NH;
    const int b = (int)(tok >> 11);
    const int t = (int)(tok & 2047);
    const int c = t / CHUNK;
    const int tid = threadIdx.x;
    const int d = tid * 2;
    float2 uu = *(const float2*)&U[tok * (size_t)VD + h * HD + d];
    float  P  = pp[tok * NH + h];
    float2 cy = *(const float2*)&carry[((size_t)(b * NH + h) * NC + c) * HD + d];
    float u0 = fmaf(P, cy.x, uu.x);
    float u1 = fmaf(P, cy.y, uu.y);
    float s = u0 * u0 + u1 * u1;
    for (int off = 32; off; off >>= 1) s += __shfl_down(s, off);
    __shared__ float r4[4];
    const int lane = tid & 63, wv = tid >> 6;
    if (lane == 0) r4[wv] = s;
    __syncthreads();
    float tot = r4[0] + r4[1] + r4[2] + r4[3];
    float rms = rsqrtf(tot * (1.f / 512.f) + 1e-5f);
    float g0 = g[tok * (size_t)VD + h * HD + d];
    float g1 = g[tok * (size_t)VD + h * HD + d + 1];
    float si0 = g0 / (1.f + expf(-g0));
    float si1 = g1 / (1.f + expf(-g1));
    float o0 = u0 * rms * rms_w[d]     * si0;
    float o1 = u1 * rms * rms_w[d + 1] * si1;
    *(float2*)&O[tok * (size_t)VD + h * HD + d] = float2{o0, o1};
}

// ----------------------------------------------------------------
extern "C" void kernel_launch(void* const* d_in, const int* in_sizes, int n_in,
                              void* d_out, int out_size, void* d_ws, size_t ws_size,
                              hipStream_t stream) {
    const float* hs   = (const float*)d_in[0];
    const float* Wq   = (const float*)d_in[1];
    const float* Wk   = (const float*)d_in[2];
    const float* Wv   = (const float*)d_in[3];
    const float* Wa   = (const float*)d_in[4];
    const float* Wb   = (const float*)d_in[5];
    const float* Wg   = (const float*)d_in[6];
    const float* Wo   = (const float*)d_in[7];
    const float* cq   = (const float*)d_in[8];
    const float* ck   = (const float*)d_in[9];
    const float* cv   = (const float*)d_in[10];
    const float* rmsw = (const float*)d_in[11];

    char* ws = (char*)d_ws;
    size_t off = 0;
    auto alloc = [&](size_t bytes) -> void* {
        void* p = ws + off;
        off = (off + bytes + 255) & ~(size_t)255;
        return p;
    };
    float* qe    = (float*)alloc((size_t)TOKENS * 1536 * 4);   // 25.2 MB   (later: O, first half)
    float* ke    = (float*)alloc((size_t)TOKENS * 1536 * 4);   // 25.2 MB   (later: O, second half)
    float* v     = (float*)alloc((size_t)TOKENS * VD * 4);     // 50.3 MB   (later: g)
    float* U     = (float*)alloc((size_t)TOKENS * VD * 4);     // 50.3 MB
    float* alp   = (float*)alloc((size_t)TOKENS * NH * 4);
    float* bet   = (float*)alloc((size_t)TOKENS * NH * 4);
    float* pp    = (float*)alloc((size_t)TOKENS * NH * 4);
    float* carry = (float*)alloc((size_t)2 * NH * NC * HD * 4);
    float* g     = v;    // alias: v dead after k_scan1f, g computed after
    float* O     = qe;   // alias: qe+ke (50.33 MB contiguous, dead after k_scan1f)

    k_ab<<<TOKENS, 256, 0, stream>>>(hs, Wa, Wb, alp, bet);
    // q_even = hs @ Wq[:, even-gathered]   (M=4096, N=1536, K=2048)
    k_ngemm<<<dim3(1536 / 64, TOKENS / 64), 256, 0, stream>>>(hs, Wq, qe, TOKENS, 1536, HID, VD, 1);
    k_ngemm<<<dim3(1536 / 64, TOKENS / 64), 256, 0, stream>>>(hs, Wk, ke, TOKENS, 1536, HID, VD, 1);
    // v = hs @ Wv                          (M=4096, N=3072, K=2048)
    k_ngemm<<<dim3(VD / 64, TOKENS / 64), 256, 0, stream>>>(hs, Wv, v, TOKENS, VD, HID, VD, 0);
    k_scan1f<<<2 * NH * NC, 256, 0, stream>>>(qe, ke, v, alp, bet, cq, ck, cv, U, pp);
    k_carry<<<2 * NH, 256, 0, stream>>>(U, pp, carry);
    // g = hs @ Wg  (into v's buffer — v is dead now)
    k_ngemm<<<dim3(VD / 64, TOKENS / 64), 256, 0, stream>>>(hs, Wg, g, TOKENS, VD, HID, VD, 0);
    k_pass3f<<<TOKENS * NH, 256, 0, stream>>>(U, pp, carry, g, rmsw, O);
    // out = O @ Wo                         (M=4096, N=2048, K=3072), f32 store
    k_ngemm<<<dim3(HID / 64, TOKENS / 64), 256, 0, stream>>>(O, Wo, (float*)d_out, TOKENS, HID, VD, HID, 0);
}

// Round 4
// 447.712 us; speedup vs baseline: 10.3341x; 10.3341x over previous
//
#include <hip/hip_runtime.h>
#include <hip/hip_bf16.h>
#include <stdint.h>

using bf16 = __hip_bfloat16;
using mfrag = __attribute__((ext_vector_type(8))) __bf16;   // 8 bf16 = 4 VGPRs
using f32x4 = __attribute__((ext_vector_type(4))) float;

#define TOKENS 4096
#define HID    2048
#define VD     3072
#define NH     6
#define HD     512
#define NPAIR  256
#define N1     9216     /* q_even(1536) | k_even(1536) | v(3072) | g(3072) */
#define NC     32
#define CHUNK  64

__device__ __forceinline__ void gld_lds16(const bf16* g, bf16* l) {
    __builtin_amdgcn_global_load_lds((const __attribute__((address_space(1))) void*)g,
                                     (__attribute__((address_space(3))) void*)l, 16, 0, 0);
}

// ---------------------------------------------------------------- GEMM (m97 structure)
// A: (M,K) bf16 row-major; Bt: (N,K) bf16 row-major (i.e. B^T).
// C: (M,N), bf16 if obf else f32.  128x128 tile, BK=64, 4 waves (2x2), 4x4 16x16x32 frags.
__global__ __launch_bounds__(256) void k_gemm(const bf16* __restrict__ A,
                                              const bf16* __restrict__ Bt,
                                              void* __restrict__ Cv,
                                              int M, int N, int K, int obf) {
    __shared__ bf16 sA[128 * 64];
    __shared__ bf16 sB[128 * 64];
    const int tid  = threadIdx.x;
    const int wave = tid >> 6;
    const int lane = tid & 63;
    const int bm = blockIdx.y * 128;
    const int bn = blockIdx.x * 128;
    const int wr = (wave >> 1) * 64;
    const int wc = (wave & 1) * 64;
    const int lrow = lane & 15;
    const int lk   = lane >> 4;

    f32x4 acc[4][4];
#pragma unroll
    for (int m = 0; m < 4; ++m)
#pragma unroll
        for (int n = 0; n < 4; ++n) acc[m][n] = f32x4{0.f, 0.f, 0.f, 0.f};

    for (int kt = 0; kt < K; kt += 64) {
#pragma unroll
        for (int i = 0; i < 4; ++i) {
            const int flat = i * 256 + tid;
            const int row = flat >> 3, c8 = flat & 7;
            const int fw = i * 256 + wave * 64;   // wave-uniform LDS base (lane adds *16B)
            gld_lds16(A  + (size_t)(bm + row) * K + kt + c8 * 8, sA + fw * 8);
            gld_lds16(Bt + (size_t)(bn + row) * K + kt + c8 * 8, sB + fw * 8);
        }
        __syncthreads();   // compiler drains vmcnt before barrier
#pragma unroll
        for (int ks = 0; ks < 2; ++ks) {
            mfrag af[4], bfr[4];
#pragma unroll
            for (int m = 0; m < 4; ++m)
                af[m] = *(const mfrag*)&sA[(wr + m * 16 + lrow) * 64 + ks * 32 + lk * 8];
#pragma unroll
            for (int n = 0; n < 4; ++n)
                bfr[n] = *(const mfrag*)&sB[(wc + n * 16 + lrow) * 64 + ks * 32 + lk * 8];
#pragma unroll
            for (int m = 0; m < 4; ++m)
#pragma unroll
                for (int n = 0; n < 4; ++n)
                    acc[m][n] = __builtin_amdgcn_mfma_f32_16x16x32_bf16(af[m], bfr[n], acc[m][n], 0, 0, 0);
        }
        __syncthreads();
    }
#pragma unroll
    for (int m = 0; m < 4; ++m)
#pragma unroll
        for (int j = 0; j < 4; ++j) {
            const int r = bm + wr + m * 16 + lk * 4 + j;
#pragma unroll
            for (int n = 0; n < 4; ++n) {
                const int c = bn + wc + n * 16 + lrow;
                if (obf) ((bf16*)Cv)[(size_t)r * N + c] = __float2bfloat16(acc[m][n][j]);
                else     ((float*)Cv)[(size_t)r * N + c] = acc[m][n][j];
            }
        }
}

// ---------------------------------------------------------------- f32 -> bf16 cast
__global__ void k_cast_bf16(const float* __restrict__ in, bf16* __restrict__ out, int n) {
    int i = (blockIdx.x * 256 + threadIdx.x) * 4;
    if (i >= n) return;
    float4 v = *(const float4*)(in + i);
    out[i + 0] = __float2bfloat16(v.x);
    out[i + 1] = __float2bfloat16(v.y);
    out[i + 2] = __float2bfloat16(v.z);
    out[i + 3] = __float2bfloat16(v.w);
}

// ---------------------------------------------------------------- fused weight build:
// Wt[n][k] (9216 x 2048 bf16) = selected column col(n) of Wq/Wk(even)/Wv/Wg.
__global__ void k_prep_w(const float* __restrict__ Wq, const float* __restrict__ Wk,
                         const float* __restrict__ Wv, const float* __restrict__ Wg,
                         bf16* __restrict__ Wt) {
    __shared__ float t[32][33];
    const int n0 = blockIdx.x * 32;
    const int k0 = blockIdx.y * 32;
    const int tx = threadIdx.x, ty = threadIdx.y;
    const float* src; int cb, cs;
    if (n0 < 1536)      { int m = n0;        src = Wq; cb = (m >> 8) * 512 + (m & 255) * 2; cs = 2; }
    else if (n0 < 3072) { int m = n0 - 1536; src = Wk; cb = (m >> 8) * 512 + (m & 255) * 2; cs = 2; }
    else if (n0 < 6144) { int m = n0 - 3072; src = Wv; cb = m; cs = 1; }
    else                { int m = n0 - 6144; src = Wg; cb = m; cs = 1; }
#pragma unroll
    for (int i = 0; i < 4; ++i) {
        int k = k0 + ty + i * 8;
        t[ty + i * 8][tx] = src[(size_t)k * VD + cb + cs * tx];
    }
    __syncthreads();
#pragma unroll
    for (int i = 0; i < 4; ++i) {
        int n = n0 + ty + i * 8;
        Wt[(size_t)n * HID + k0 + tx] = __float2bfloat16(t[tx][ty + i * 8]);
    }
}

// ---------------------------------------------------------------- transpose+cast: dst[c][r] = src[r][c]
__global__ void k_tr_cast(const float* __restrict__ src, bf16* __restrict__ dst, int R, int Ccol) {
    __shared__ float t[32][33];
    const int c0 = blockIdx.x * 32, r0 = blockIdx.y * 32;
    const int tx = threadIdx.x, ty = threadIdx.y;
#pragma unroll
    for (int i = 0; i < 4; ++i)
        t[ty + i * 8][tx] = src[(size_t)(r0 + ty + i * 8) * Ccol + c0 + tx];
    __syncthreads();
#pragma unroll
    for (int i = 0; i < 4; ++i)
        dst[(size_t)(c0 + ty + i * 8) * R + r0 + tx] = __float2bfloat16(t[tx][ty + i * 8]);
}

// ---------------------------------------------------------------- alpha/beta (tiny GEMM + sigmoid)
__global__ __launch_bounds__(256) void k_ab(const float* __restrict__ hs, const float* __restrict__ Wa,
                                            const float* __restrict__ Wb,
                                            float* __restrict__ alpha, float* __restrict__ beta) {
    const int tok = blockIdx.x;
    const int tid = threadIdx.x;
    float part[12];
#pragma unroll
    for (int j = 0; j < 12; ++j) part[j] = 0.f;
    const float* hrow = hs + (size_t)tok * HID;
    for (int i = 0; i < 8; ++i) {
        int k = i * 256 + tid;
        float x = hrow[k];
        const float* wa = Wa + k * NH;
        const float* wb = Wb + k * NH;
#pragma unroll
        for (int j = 0; j < NH; ++j) {
            part[j]     = fmaf(x, wa[j], part[j]);
            part[6 + j] = fmaf(x, wb[j], part[6 + j]);
        }
    }
    __shared__ float red[12][4];
    const int lane = tid & 63, wv = tid >> 6;
#pragma unroll
    for (int j = 0; j < 12; ++j) {
        float s = part[j];
        for (int off = 32; off; off >>= 1) s += __shfl_down(s, off);
        if (lane == 0) red[j][wv] = s;
    }
    __syncthreads();
    if (tid < 12) {
        float s = red[tid][0] + red[tid][1] + red[tid][2] + red[tid][3];
        float v = 1.f / (1.f + expf(-s));
        if (tid < 6) alpha[(size_t)tok * NH + tid] = v;
        else         beta [(size_t)tok * NH + tid - 6] = v;
    }
}

// ---------------------------------------------------------------- conv + phase + rotate + local chunk scan
__global__ __launch_bounds__(256) void k_scan1(const bf16* __restrict__ X,
                                               const float* __restrict__ alpha,
                                               const float* __restrict__ beta,
                                               const float* __restrict__ cq,
                                               const float* __restrict__ ck,
                                               const float* __restrict__ cv,
                                               float* __restrict__ U, float* __restrict__ pp) {
    const int bx = blockIdx.x;
    const int c  = bx & (NC - 1);
    const int h  = (bx >> 5) % NH;
    const int b  = bx / (NC * NH);
    const int p  = threadIdx.x;
    const int t0 = c * CHUNK;
    const int ch2 = h * HD + 2 * p;
    const float wq0 = cq[ch2 * 4 + 0], wq1 = cq[ch2 * 4 + 1], wq2 = cq[ch2 * 4 + 2], wq3 = cq[ch2 * 4 + 3];
    const float wk0 = ck[ch2 * 4 + 0], wk1 = ck[ch2 * 4 + 1], wk2 = ck[ch2 * 4 + 2], wk3 = ck[ch2 * 4 + 3];
    const float wa0 = cv[ch2 * 4 + 0], wa1 = cv[ch2 * 4 + 1], wa2 = cv[ch2 * 4 + 2], wa3 = cv[ch2 * 4 + 3];
    const float wb0 = cv[(ch2 + 1) * 4 + 0], wb1 = cv[(ch2 + 1) * 4 + 1],
                wb2 = cv[(ch2 + 1) * 4 + 2], wb3 = cv[(ch2 + 1) * 4 + 3];
    const float invf = exp2f(-13.287712379549449f * ((float)p * (1.0f / 256.0f)));
    const int qcol = h * NPAIR + p;
    const int kcol = 1536 + h * NPAIR + p;
    const int vcol = 3072 + ch2;

    float xq[3], xk[3], xv0[3], xv1[3];
#pragma unroll
    for (int i = 0; i < 3; ++i) {
        int t = t0 - 3 + i;
        if (t >= 0) {
            size_t tok = (size_t)b * 2048 + t;
            const bf16* xr = X + tok * N1;
            xq[i] = __bfloat162float(xr[qcol]);
            xk[i] = __bfloat162float(xr[kcol]);
            __hip_bfloat162 vv = *(const __hip_bfloat162*)&xr[vcol];
            xv0[i] = __bfloat162float(vv.x);
            xv1[i] = __bfloat162float(vv.y);
        } else { xq[i] = xk[i] = xv0[i] = xv1[i] = 0.f; }
    }

    float u0 = 0.f, u1 = 0.f, ap = 1.f;
    for (int t = t0; t < t0 + CHUNK; ++t) {
        const size_t tok = (size_t)b * 2048 + t;
        const bf16* xr = X + tok * N1;
        float nq = __bfloat162float(xr[qcol]);
        float nk = __bfloat162float(xr[kcol]);
        __hip_bfloat162 vv = *(const __hip_bfloat162*)&xr[vcol];
        float nv0 = __bfloat162float(vv.x);
        float nv1 = __bfloat162float(vv.y);
        float yq  = wq3 * nq  + wq2 * xq[2]  + wq1 * xq[1]  + wq0 * xq[0];
        float yk  = wk3 * nk  + wk2 * xk[2]  + wk1 * xk[1]  + wk0 * xk[0];
        float yv0 = wa3 * nv0 + wa2 * xv0[2] + wa1 * xv0[1] + wa0 * xv0[0];
        float yv1 = wb3 * nv1 + wb2 * xv1[2] + wb1 * xv1[1] + wb0 * xv1[0];
        xq[0] = xq[1]; xq[1] = xq[2]; xq[2] = nq;
        xk[0] = xk[1]; xk[1] = xk[2]; xk[2] = nk;
        xv0[0] = xv0[1]; xv0[1] = xv0[2]; xv0[2] = nv0;
        xv1[0] = xv1[1]; xv1[1] = xv1[2]; xv1[2] = nv1;
        float theta = yq * invf, psi = yk * invf;
        float d = psi - theta, sn, cs;
        __sincosf(d, &sn, &cs);
        float w0 = yv0 * cs - yv1 * sn;
        float w1 = yv1 * cs + yv0 * sn;
        float a  = alpha[tok * NH + h];
        float bb = beta [tok * NH + h];
        u0 = fmaf(a, u0, bb * w0);
        u1 = fmaf(a, u1, bb * w1);
        ap *= a;
        *(float2*)&U[tok * (size_t)VD + h * HD + 2 * p] = float2{u0, u1};
        if (p == 0) pp[tok * NH + h] = ap;
    }
}

// ---------------------------------------------------------------- cross-chunk carry
__global__ void k_carry(const float* __restrict__ U, const float* __restrict__ pp,
                        float* __restrict__ carry) {
    const int bh = blockIdx.x;              // 0..11 = b*NH+h
    const int b = bh / NH, h = bh % NH;
    const int tid = threadIdx.x;
    for (int half = 0; half < 2; ++half) {
        const int d = tid + half * 256;
        float s = 0.f;
        for (int c = 0; c < NC; ++c) {
            carry[((size_t)bh * NC + c) * HD + d] = s;
            int tend = c * CHUNK + CHUNK - 1;
            size_t tok = (size_t)b * 2048 + tend;
            s = U[tok * (size_t)VD + h * HD + d] + pp[tok * NH + h] * s;
        }
    }
}

// ---------------------------------------------------------------- carry fix + RMS + SiLU gate -> bf16 O
__global__ __launch_bounds__(256) void k_pass3(const float* __restrict__ U, const float* __restrict__ pp,
                                               const float* __restrict__ carry, const bf16* __restrict__ X,
                                               const float* __restrict__ rms_w, bf16* __restrict__ O) {
    const int bx = blockIdx.x;              // tok*NH + h
    const int h = bx % NH;
    const size_t tok = bx / NH;
    const int b = (int)(tok >> 11);
    const int t = (int)(tok & 2047);
    const int c = t / CHUNK;
    const int tid = threadIdx.x;
    const int d = tid * 2;
    float2 uu = *(const float2*)&U[tok * (size_t)VD + h * HD + d];
    float  P  = pp[tok * NH + h];
    float2 cy = *(const float2*)&carry[((size_t)(b * NH + h) * NC + c) * HD + d];
    float u0 = fmaf(P, cy.x, uu.x);
    float u1 = fmaf(P, cy.y, uu.y);
    float s = u0 * u0 + u1 * u1;
    for (int off = 32; off; off >>= 1) s += __shfl_down(s, off);
    __shared__ float r4[4];
    const int lane = tid & 63, wv = tid >> 6;
    if (lane == 0) r4[wv] = s;
    __syncthreads();
    float tot = r4[0] + r4[1] + r4[2] + r4[3];
    float rms = rsqrtf(tot * (1.f / 512.f) + 1e-5f);
    __hip_bfloat162 gg = *(const __hip_bfloat162*)&X[tok * N1 + 6144 + h * HD + d];
    float g0 = __bfloat162float(gg.x), g1 = __bfloat162float(gg.y);
    float si0 = g0 / (1.f + expf(-g0));
    float si1 = g1 / (1.f + expf(-g1));
    float o0 = u0 * rms * rms_w[d]     * si0;
    float o1 = u1 * rms * rms_w[d + 1] * si1;
    __hip_bfloat162 ob;
    ob.x = __float2bfloat16(o0);
    ob.y = __float2bfloat16(o1);
    *(__hip_bfloat162*)&O[tok * (size_t)VD + h * HD + d] = ob;
}

// ----------------------------------------------------------------
extern "C" void kernel_launch(void* const* d_in, const int* in_sizes, int n_in,
                              void* d_out, int out_size, void* d_ws, size_t ws_size,
                              hipStream_t stream) {
    const float* hs   = (const float*)d_in[0];
    const float* Wq   = (const float*)d_in[1];
    const float* Wk   = (const float*)d_in[2];
    const float* Wv   = (const float*)d_in[3];
    const float* Wa   = (const float*)d_in[4];
    const float* Wb   = (const float*)d_in[5];
    const float* Wg   = (const float*)d_in[6];
    const float* Wo   = (const float*)d_in[7];
    const float* cq   = (const float*)d_in[8];
    const float* ck   = (const float*)d_in[9];
    const float* cv   = (const float*)d_in[10];
    const float* rmsw = (const float*)d_in[11];

    char* ws = (char*)d_ws;
    size_t off = 0;
    auto alloc = [&](size_t bytes) -> void* {
        void* p = ws + off;
        off = (off + bytes + 255) & ~(size_t)255;
        return p;
    };
    bf16*  hsb   = (bf16*) alloc((size_t)TOKENS * HID * 2);       // 16.8 MB
    bf16*  Wt    = (bf16*) alloc((size_t)N1 * HID * 2);           // 37.7 MB
    bf16*  Wot   = (bf16*) alloc((size_t)HID * VD * 2);           // 12.6 MB
    bf16*  X     = (bf16*) alloc((size_t)TOKENS * N1 * 2);        // 75.5 MB
    float* U     = (float*)alloc((size_t)TOKENS * VD * 4);        // 50.3 MB
    float* alp   = (float*)alloc((size_t)TOKENS * NH * 4);
    float* bet   = (float*)alloc((size_t)TOKENS * NH * 4);
    float* pp    = (float*)alloc((size_t)TOKENS * NH * 4);
    float* carry = (float*)alloc((size_t)2 * NH * NC * HD * 4);
    bf16*  O     = (bf16*)Wt;   // alias: Wt dead after GEMM-1, O written after

    k_cast_bf16<<<TOKENS * HID / 1024, 256, 0, stream>>>(hs, hsb, TOKENS * HID);
    k_prep_w<<<dim3(N1 / 32, HID / 32), dim3(32, 8), 0, stream>>>(Wq, Wk, Wv, Wg, Wt);
    k_tr_cast<<<dim3(HID / 32, VD / 32), dim3(32, 8), 0, stream>>>(Wo, Wot, VD, HID);
    k_ab<<<TOKENS, 256, 0, stream>>>(hs, Wa, Wb, alp, bet);
    // X = hsb @ Wt^T   (M=4096, N=9216, K=2048), bf16 out
    k_gemm<<<dim3(N1 / 128, TOKENS / 128), 256, 0, stream>>>(hsb, Wt, X, TOKENS, N1, HID, 1);
    k_scan1<<<2 * NH * NC, 256, 0, stream>>>(X, alp, bet, cq, ck, cv, U, pp);
    k_carry<<<2 * NH, 256, 0, stream>>>(U, pp, carry);
    k_pass3<<<TOKENS * NH, 256, 0, stream>>>(U, pp, carry, X, rmsw, O);
    // out = O @ Wot^T  (M=4096, N=2048, K=3072), f32 out -> d_out
    k_gemm<<<dim3(HID / 128, TOKENS / 128), 256, 0, stream>>>(O, Wot, d_out, TOKENS, HID, VD, 0);
}

// Round 5
// 404.899 us; speedup vs baseline: 11.4268x; 1.1057x over previous
//
#include <hip/hip_runtime.h>
#include <hip/hip_bf16.h>
#include <stdint.h>

using bf16 = __hip_bfloat16;
using mfrag = __attribute__((ext_vector_type(8))) __bf16;   // 8 bf16 = 4 VGPRs
using f32x4 = __attribute__((ext_vector_type(4))) float;

#define TOKENS 4096
#define HID    2048
#define VD     3072
#define NH     6
#define HD     512
#define NPAIR  256
#define N1     9216     /* q_even(1536) | k_even(1536) | v(3072) | g(3072) */
#define NC     32
#define CHUNK  64

// pipelined GEMM geometry
#define BM    256
#define BN    128
#define BK    64
#define SLOT_A_BYTES (BM * BK * 2)            /* 32768 */
#define SLOT_BYTES   (SLOT_A_BYTES + BN * BK * 2)  /* 49152 */
#define RING  3
#define SMEM_BYTES (RING * SLOT_BYTES)        /* 147456 */

__device__ __forceinline__ void gld_lds16(const bf16* g, bf16* l) {
    __builtin_amdgcn_global_load_lds((const __attribute__((address_space(1))) void*)g,
                                     (__attribute__((address_space(3))) void*)l, 16, 0, 0);
}

// ---------------------------------------------------------------- pipelined GEMM
// A: (M,BMxK) bf16 row-major; Bt: (N,K) bf16 row-major (B^T). C: (M,N) bf16 or f32.
// 256x128 tile, BK=64, 8 waves (4 row x 2 col), 4x4 16x16x32 frags per wave.
// 3-deep LDS ring, global_load_lds staging 3 K-tiles ahead, counted vmcnt,
// XOR-swizzled LDS chunks (swizzle applied to read addr AND global source).
__global__ __launch_bounds__(512, 2) void k_gemm_p(const bf16* __restrict__ A,
                                                   const bf16* __restrict__ Bt,
                                                   void* __restrict__ Cv,
                                                   int M, int N, int K, int obf) {
    extern __shared__ char smem[];
    const int tid  = threadIdx.x;
    const int wave = tid >> 6;
    const int lane = tid & 63;
    const int lrow = lane & 15;
    const int lk   = lane >> 4;
    const int wm   = wave >> 1;          // 0..3 (row block of 64)
    const int wn   = wave & 1;           // 0..1 (col block of 64)

    // XCD-aware bijective swizzle (grid sizes here are multiples of 8)
    const int nbn = N >> 7;
    const int nwg = gridDim.x;
    const int cpx = nwg >> 3;
    const int bid = blockIdx.x;
    const int swz = (bid & 7) * cpx + (bid >> 3);
    const int bm  = (swz / nbn) << 8;
    const int bn  = (swz % nbn) << 7;

    const int NT = K >> 6;

    // stage tile `t` (global k-offset t*64) into ring slot at `sbase`.
    // LDS dest is linear; source chunk is XOR-pre-swizzled (rule 21).
    auto STAGE = [&](int t, char* sbase) {
        const int koff = t << 6;
#pragma unroll
        for (int i = 0; i < 4; ++i) {            // A: 256 rows x 8 chunks
            const int L   = i * 512 + tid;
            const int row = L >> 3;
            const int cl  = (L & 7) ^ (row & 7); // logical chunk to fetch
            const bf16* g = A + (size_t)(bm + row) * K + koff + cl * 8;
            bf16* l = (bf16*)(sbase + (size_t)(i * 512 + wave * 64) * 16);
            gld_lds16(g, l);
        }
#pragma unroll
        for (int i = 0; i < 2; ++i) {            // B: 128 rows x 8 chunks
            const int L   = i * 512 + tid;
            const int row = L >> 3;
            const int cl  = (L & 7) ^ (row & 7);
            const bf16* g = Bt + (size_t)(bn + row) * K + koff + cl * 8;
            bf16* l = (bf16*)(sbase + SLOT_A_BYTES + (size_t)(i * 512 + wave * 64) * 16);
            gld_lds16(g, l);
        }
    };

    f32x4 acc[4][4];
#pragma unroll
    for (int m = 0; m < 4; ++m)
#pragma unroll
        for (int n = 0; n < 4; ++n) acc[m][n] = f32x4{0.f, 0.f, 0.f, 0.f};

    // prologue: stage tiles 0,1,2; wait for tile 0 (12 = tiles 1,2 in flight)
    STAGE(0, smem);
    STAGE(1, smem + SLOT_BYTES);
    STAGE(2, smem + 2 * SLOT_BYTES);
    asm volatile("s_waitcnt vmcnt(12)" ::: "memory");
    __builtin_amdgcn_sched_barrier(0);
    __builtin_amdgcn_s_barrier();

    int slotoff = 0;
    for (int t = 0; t < NT; ++t) {
        char* sbase = smem + slotoff;
        const char* sa = sbase;
        const char* sb = sbase + SLOT_A_BYTES;

        // ---- phase 1a: read all fragments of tile t (swizzled chunks)
        mfrag a[4][2], b[4][2];
#pragma unroll
        for (int m = 0; m < 4; ++m) {
            const int r = wm * 64 + m * 16 + lrow;
#pragma unroll
            for (int kk = 0; kk < 2; ++kk) {
                const int c = (kk * 4 + lk) ^ (r & 7);
                a[m][kk] = *(const mfrag*)(sa + (size_t)r * 128 + c * 16);
            }
        }
#pragma unroll
        for (int n = 0; n < 4; ++n) {
            const int r = wn * 64 + n * 16 + lrow;
#pragma unroll
            for (int kk = 0; kk < 2; ++kk) {
                const int c = (kk * 4 + lk) ^ (r & 7);
                b[n][kk] = *(const mfrag*)(sb + (size_t)r * 128 + c * 16);
            }
        }
        asm volatile("s_waitcnt lgkmcnt(0)" ::: "memory");
        __builtin_amdgcn_sched_barrier(0);
        __builtin_amdgcn_s_barrier();            // all waves done reading this slot

        // ---- phase 1b: stage tile t+3 into the slot just freed; MFMA kk=0
        if (t + 3 < NT) STAGE(t + 3, sbase);
        __builtin_amdgcn_s_setprio(1);
#pragma unroll
        for (int m = 0; m < 4; ++m)
#pragma unroll
            for (int n = 0; n < 4; ++n)
                acc[m][n] = __builtin_amdgcn_mfma_f32_16x16x32_bf16(a[m][0], b[n][0], acc[m][n], 0, 0, 0);
        __builtin_amdgcn_s_setprio(0);

        // ---- phase 2: MFMA kk=1
        __builtin_amdgcn_s_setprio(1);
#pragma unroll
        for (int m = 0; m < 4; ++m)
#pragma unroll
            for (int n = 0; n < 4; ++n)
                acc[m][n] = __builtin_amdgcn_mfma_f32_16x16x32_bf16(a[m][1], b[n][1], acc[m][n], 0, 0, 0);
        __builtin_amdgcn_s_setprio(0);

        // ---- end of tile: ensure tile t+1 landed (counted, never drains pipe)
        if (t + 3 < NT)      { asm volatile("s_waitcnt vmcnt(12)" ::: "memory"); }
        else if (t + 2 < NT) { asm volatile("s_waitcnt vmcnt(6)"  ::: "memory"); }
        else                 { asm volatile("s_waitcnt vmcnt(0)"  ::: "memory"); }
        __builtin_amdgcn_sched_barrier(0);
        __builtin_amdgcn_s_barrier();

        slotoff += SLOT_BYTES;
        if (slotoff == SMEM_BYTES) slotoff = 0;
    }

    // ---- epilogue
#pragma unroll
    for (int m = 0; m < 4; ++m)
#pragma unroll
        for (int j = 0; j < 4; ++j) {
            const int r = bm + wm * 64 + m * 16 + lk * 4 + j;
#pragma unroll
            for (int n = 0; n < 4; ++n) {
                const int c = bn + wn * 64 + n * 16 + lrow;
                if (obf) ((bf16*)Cv)[(size_t)r * N + c] = __float2bfloat16(acc[m][n][j]);
                else     ((float*)Cv)[(size_t)r * N + c] = acc[m][n][j];
            }
        }
}

// ---------------------------------------------------------------- f32 -> bf16 cast
__global__ void k_cast_bf16(const float* __restrict__ in, bf16* __restrict__ out, int n) {
    int i = (blockIdx.x * 256 + threadIdx.x) * 4;
    if (i >= n) return;
    float4 v = *(const float4*)(in + i);
    out[i + 0] = __float2bfloat16(v.x);
    out[i + 1] = __float2bfloat16(v.y);
    out[i + 2] = __float2bfloat16(v.z);
    out[i + 3] = __float2bfloat16(v.w);
}

// ---------------------------------------------------------------- fused weight build:
// Wt[n][k] (9216 x 2048 bf16) = selected column col(n) of Wq/Wk(even)/Wv/Wg.
__global__ void k_prep_w(const float* __restrict__ Wq, const float* __restrict__ Wk,
                         const float* __restrict__ Wv, const float* __restrict__ Wg,
                         bf16* __restrict__ Wt) {
    __shared__ float t[32][33];
    const int n0 = blockIdx.x * 32;
    const int k0 = blockIdx.y * 32;
    const int tx = threadIdx.x, ty = threadIdx.y;
    const float* src; int cb, cs;
    if (n0 < 1536)      { int m = n0;        src = Wq; cb = (m >> 8) * 512 + (m & 255) * 2; cs = 2; }
    else if (n0 < 3072) { int m = n0 - 1536; src = Wk; cb = (m >> 8) * 512 + (m & 255) * 2; cs = 2; }
    else if (n0 < 6144) { int m = n0 - 3072; src = Wv; cb = m; cs = 1; }
    else                { int m = n0 - 6144; src = Wg; cb = m; cs = 1; }
#pragma unroll
    for (int i = 0; i < 4; ++i) {
        int k = k0 + ty + i * 8;
        t[ty + i * 8][tx] = src[(size_t)k * VD + cb + cs * tx];
    }
    __syncthreads();
#pragma unroll
    for (int i = 0; i < 4; ++i) {
        int n = n0 + ty + i * 8;
        Wt[(size_t)n * HID + k0 + tx] = __float2bfloat16(t[tx][ty + i * 8]);
    }
}

// ---------------------------------------------------------------- transpose+cast: dst[c][r] = src[r][c]
__global__ void k_tr_cast(const float* __restrict__ src, bf16* __restrict__ dst, int R, int Ccol) {
    __shared__ float t[32][33];
    const int c0 = blockIdx.x * 32, r0 = blockIdx.y * 32;
    const int tx = threadIdx.x, ty = threadIdx.y;
#pragma unroll
    for (int i = 0; i < 4; ++i)
        t[ty + i * 8][tx] = src[(size_t)(r0 + ty + i * 8) * Ccol + c0 + tx];
    __syncthreads();
#pragma unroll
    for (int i = 0; i < 4; ++i)
        dst[(size_t)(c0 + ty + i * 8) * R + r0 + tx] = __float2bfloat16(t[tx][ty + i * 8]);
}

// ---------------------------------------------------------------- alpha/beta (tiny GEMM + sigmoid)
__global__ __launch_bounds__(256) void k_ab(const float* __restrict__ hs, const float* __restrict__ Wa,
                                            const float* __restrict__ Wb,
                                            float* __restrict__ alpha, float* __restrict__ beta) {
    const int tok = blockIdx.x;
    const int tid = threadIdx.x;
    float part[12];
#pragma unroll
    for (int j = 0; j < 12; ++j) part[j] = 0.f;
    const float* hrow = hs + (size_t)tok * HID;
    for (int i = 0; i < 8; ++i) {
        int k = i * 256 + tid;
        float x = hrow[k];
        const float* wa = Wa + k * NH;
        const float* wb = Wb + k * NH;
#pragma unroll
        for (int j = 0; j < NH; ++j) {
            part[j]     = fmaf(x, wa[j], part[j]);
            part[6 + j] = fmaf(x, wb[j], part[6 + j]);
        }
    }
    __shared__ float red[12][4];
    const int lane = tid & 63, wv = tid >> 6;
#pragma unroll
    for (int j = 0; j < 12; ++j) {
        float s = part[j];
        for (int off = 32; off; off >>= 1) s += __shfl_down(s, off);
        if (lane == 0) red[j][wv] = s;
    }
    __syncthreads();
    if (tid < 12) {
        float s = red[tid][0] + red[tid][1] + red[tid][2] + red[tid][3];
        float v = 1.f / (1.f + expf(-s));
        if (tid < 6) alpha[(size_t)tok * NH + tid] = v;
        else         beta [(size_t)tok * NH + tid - 6] = v;
    }
}

// ---------------------------------------------------------------- conv + phase + rotate + local chunk scan
__global__ __launch_bounds__(256) void k_scan1(const bf16* __restrict__ X,
                                               const float* __restrict__ alpha,
                                               const float* __restrict__ beta,
                                               const float* __restrict__ cq,
                                               const float* __restrict__ ck,
                                               const float* __restrict__ cv,
                                               float* __restrict__ U, float* __restrict__ pp) {
    const int bx = blockIdx.x;
    const int c  = bx & (NC - 1);
    const int h  = (bx >> 5) % NH;
    const int b  = bx / (NC * NH);
    const int p  = threadIdx.x;
    const int t0 = c * CHUNK;
    const int ch2 = h * HD + 2 * p;
    const float wq0 = cq[ch2 * 4 + 0], wq1 = cq[ch2 * 4 + 1], wq2 = cq[ch2 * 4 + 2], wq3 = cq[ch2 * 4 + 3];
    const float wk0 = ck[ch2 * 4 + 0], wk1 = ck[ch2 * 4 + 1], wk2 = ck[ch2 * 4 + 2], wk3 = ck[ch2 * 4 + 3];
    const float wa0 = cv[ch2 * 4 + 0], wa1 = cv[ch2 * 4 + 1], wa2 = cv[ch2 * 4 + 2], wa3 = cv[ch2 * 4 + 3];
    const float wb0 = cv[(ch2 + 1) * 4 + 0], wb1 = cv[(ch2 + 1) * 4 + 1],
                wb2 = cv[(ch2 + 1) * 4 + 2], wb3 = cv[(ch2 + 1) * 4 + 3];
    const float invf = exp2f(-13.287712379549449f * ((float)p * (1.0f / 256.0f)));
    const int qcol = h * NPAIR + p;
    const int kcol = 1536 + h * NPAIR + p;
    const int vcol = 3072 + ch2;

    float xq[3], xk[3], xv0[3], xv1[3];
#pragma unroll
    for (int i = 0; i < 3; ++i) {
        int t = t0 - 3 + i;
        if (t >= 0) {
            size_t tok = (size_t)b * 2048 + t;
            const bf16* xr = X + tok * N1;
            xq[i] = __bfloat162float(xr[qcol]);
            xk[i] = __bfloat162float(xr[kcol]);
            __hip_bfloat162 vv = *(const __hip_bfloat162*)&xr[vcol];
            xv0[i] = __bfloat162float(vv.x);
            xv1[i] = __bfloat162float(vv.y);
        } else { xq[i] = xk[i] = xv0[i] = xv1[i] = 0.f; }
    }

    float u0 = 0.f, u1 = 0.f, ap = 1.f;
    for (int t = t0; t < t0 + CHUNK; ++t) {
        const size_t tok = (size_t)b * 2048 + t;
        const bf16* xr = X + tok * N1;
        float nq = __bfloat162float(xr[qcol]);
        float nk = __bfloat162float(xr[kcol]);
        __hip_bfloat162 vv = *(const __hip_bfloat162*)&xr[vcol];
        float nv0 = __bfloat162float(vv.x);
        float nv1 = __bfloat162float(vv.y);
        float yq  = wq3 * nq  + wq2 * xq[2]  + wq1 * xq[1]  + wq0 * xq[0];
        float yk  = wk3 * nk  + wk2 * xk[2]  + wk1 * xk[1]  + wk0 * xk[0];
        float yv0 = wa3 * nv0 + wa2 * xv0[2] + wa1 * xv0[1] + wa0 * xv0[0];
        float yv1 = wb3 * nv1 + wb2 * xv1[2] + wb1 * xv1[1] + wb0 * xv1[0];
        xq[0] = xq[1]; xq[1] = xq[2]; xq[2] = nq;
        xk[0] = xk[1]; xk[1] = xk[2]; xk[2] = nk;
        xv0[0] = xv0[1]; xv0[1] = xv0[2]; xv0[2] = nv0;
        xv1[0] = xv1[1]; xv1[1] = xv1[2]; xv1[2] = nv1;
        float theta = yq * invf, psi = yk * invf;
        float d = psi - theta, sn, cs;
        __sincosf(d, &sn, &cs);
        float w0 = yv0 * cs - yv1 * sn;
        float w1 = yv1 * cs + yv0 * sn;
        float a  = alpha[tok * NH + h];
        float bb = beta [tok * NH + h];
        u0 = fmaf(a, u0, bb * w0);
        u1 = fmaf(a, u1, bb * w1);
        ap *= a;
        *(float2*)&U[tok * (size_t)VD + h * HD + 2 * p] = float2{u0, u1};
        if (p == 0) pp[tok * NH + h] = ap;
    }
}

// ---------------------------------------------------------------- cross-chunk carry
__global__ void k_carry(const float* __restrict__ U, const float* __restrict__ pp,
                        float* __restrict__ carry) {
    const int bh = blockIdx.x;              // 0..11 = b*NH+h
    const int b = bh / NH, h = bh % NH;
    const int tid = threadIdx.x;
    for (int half = 0; half < 2; ++half) {
        const int d = tid + half * 256;
        float s = 0.f;
        for (int c = 0; c < NC; ++c) {
            carry[((size_t)bh * NC + c) * HD + d] = s;
            int tend = c * CHUNK + CHUNK - 1;
            size_t tok = (size_t)b * 2048 + tend;
            s = U[tok * (size_t)VD + h * HD + d] + pp[tok * NH + h] * s;
        }
    }
}

// ---------------------------------------------------------------- carry fix + RMS + SiLU gate -> bf16 O
__global__ __launch_bounds__(256) void k_pass3(const float* __restrict__ U, const float* __restrict__ pp,
                                               const float* __restrict__ carry, const bf16* __restrict__ X,
                                               const float* __restrict__ rms_w, bf16* __restrict__ O) {
    const int bx = blockIdx.x;              // tok*NH + h
    const int h = bx % NH;
    const size_t tok = bx / NH;
    const int b = (int)(tok >> 11);
    const int t = (int)(tok & 2047);
    const int c = t / CHUNK;
    const int tid = threadIdx.x;
    const int d = tid * 2;
    float2 uu = *(const float2*)&U[tok * (size_t)VD + h * HD + d];
    float  P  = pp[tok * NH + h];
    float2 cy = *(const float2*)&carry[((size_t)(b * NH + h) * NC + c) * HD + d];
    float u0 = fmaf(P, cy.x, uu.x);
    float u1 = fmaf(P, cy.y, uu.y);
    float s = u0 * u0 + u1 * u1;
    for (int off = 32; off; off >>= 1) s += __shfl_down(s, off);
    __shared__ float r4[4];
    const int lane = tid & 63, wv = tid >> 6;
    if (lane == 0) r4[wv] = s;
    __syncthreads();
    float tot = r4[0] + r4[1] + r4[2] + r4[3];
    float rms = rsqrtf(tot * (1.f / 512.f) + 1e-5f);
    __hip_bfloat162 gg = *(const __hip_bfloat162*)&X[tok * N1 + 6144 + h * HD + d];
    float g0 = __bfloat162float(gg.x), g1 = __bfloat162float(gg.y);
    float si0 = g0 / (1.f + expf(-g0));
    float si1 = g1 / (1.f + expf(-g1));
    float o0 = u0 * rms * rms_w[d]     * si0;
    float o1 = u1 * rms * rms_w[d + 1] * si1;
    __hip_bfloat162 ob;
    ob.x = __float2bfloat16(o0);
    ob.y = __float2bfloat16(o1);
    *(__hip_bfloat162*)&O[tok * (size_t)VD + h * HD + d] = ob;
}

// ----------------------------------------------------------------
extern "C" void kernel_launch(void* const* d_in, const int* in_sizes, int n_in,
                              void* d_out, int out_size, void* d_ws, size_t ws_size,
                              hipStream_t stream) {
    const float* hs   = (const float*)d_in[0];
    const float* Wq   = (const float*)d_in[1];
    const float* Wk   = (const float*)d_in[2];
    const float* Wv   = (const float*)d_in[3];
    const float* Wa   = (const float*)d_in[4];
    const float* Wb   = (const float*)d_in[5];
    const float* Wg   = (const float*)d_in[6];
    const float* Wo   = (const float*)d_in[7];
    const float* cq   = (const float*)d_in[8];
    const float* ck   = (const float*)d_in[9];
    const float* cv   = (const float*)d_in[10];
    const float* rmsw = (const float*)d_in[11];

    char* ws = (char*)d_ws;
    size_t off = 0;
    auto alloc = [&](size_t bytes) -> void* {
        void* p = ws + off;
        off = (off + bytes + 255) & ~(size_t)255;
        return p;
    };
    bf16*  hsb   = (bf16*) alloc((size_t)TOKENS * HID * 2);       // 16.8 MB
    bf16*  Wt    = (bf16*) alloc((size_t)N1 * HID * 2);           // 37.7 MB
    bf16*  Wot   = (bf16*) alloc((size_t)HID * VD * 2);           // 12.6 MB
    bf16*  X     = (bf16*) alloc((size_t)TOKENS * N1 * 2);        // 75.5 MB
    float* U     = (float*)alloc((size_t)TOKENS * VD * 4);        // 50.3 MB
    float* alp   = (float*)alloc((size_t)TOKENS * NH * 4);
    float* bet   = (float*)alloc((size_t)TOKENS * NH * 4);
    float* pp    = (float*)alloc((size_t)TOKENS * NH * 4);
    float* carry = (float*)alloc((size_t)2 * NH * NC * HD * 4);
    bf16*  O     = (bf16*)Wt;   // alias: Wt dead after GEMM-1, O written after

    static int attr_set = 0;
    hipFuncSetAttribute((const void*)k_gemm_p,
                        hipFuncAttributeMaxDynamicSharedMemorySize, SMEM_BYTES);
    (void)attr_set;

    k_cast_bf16<<<TOKENS * HID / 1024, 256, 0, stream>>>(hs, hsb, TOKENS * HID);
    k_prep_w<<<dim3(N1 / 32, HID / 32), dim3(32, 8), 0, stream>>>(Wq, Wk, Wv, Wg, Wt);
    k_tr_cast<<<dim3(HID / 32, VD / 32), dim3(32, 8), 0, stream>>>(Wo, Wot, VD, HID);
    k_ab<<<TOKENS, 256, 0, stream>>>(hs, Wa, Wb, alp, bet);
    // X = hsb @ Wt^T   (M=4096, N=9216, K=2048) -> grid 16*72 = 1152 blocks
    k_gemm_p<<<dim3((TOKENS / BM) * (N1 / BN)), 512, SMEM_BYTES, stream>>>(hsb, Wt, X, TOKENS, N1, HID, 1);
    k_scan1<<<2 * NH * NC, 256, 0, stream>>>(X, alp, bet, cq, ck, cv, U, pp);
    k_carry<<<2 * NH, 256, 0, stream>>>(U, pp, carry);
    k_pass3<<<TOKENS * NH, 256, 0, stream>>>(U, pp, carry, X, rmsw, O);
    // out = O @ Wot^T  (M=4096, N=2048, K=3072) -> grid 16*16 = 256 blocks, f32 out
    k_gemm_p<<<dim3((TOKENS / BM) * (HID / BN)), 512, SMEM_BYTES, stream>>>(O, Wot, d_out, TOKENS, HID, VD, 0);
}

// Round 6
// 404.059 us; speedup vs baseline: 11.4505x; 1.0021x over previous
//
#include <hip/hip_runtime.h>
#include <hip/hip_bf16.h>
#include <stdint.h>

using bf16 = __hip_bfloat16;
using mfrag = __attribute__((ext_vector_type(8))) __bf16;   // 8 bf16 = 4 VGPRs
using f32x4 = __attribute__((ext_vector_type(4))) float;

#define TOKENS 4096
#define HID    2048
#define VD     3072
#define NH     6
#define HD     512
#define NPAIR  256
#define N1     9216     /* q_even(1536) | k_even(1536) | v(3072) | g(3072) */
#define NC     64
#define CHUNK  32

// pipelined GEMM geometry
#define BM    256
#define BN    128
#define BK    64
#define SLOT_A_BYTES (BM * BK * 2)                 /* 32768 */
#define SLOT_BYTES   (SLOT_A_BYTES + BN * BK * 2)  /* 49152 */
#define SMEM_BYTES   (2 * SLOT_BYTES)              /* 98304: 2-slot ring */

__device__ __forceinline__ void gld_lds16(const bf16* g, bf16* l) {
    __builtin_amdgcn_global_load_lds((const __attribute__((address_space(1))) void*)g,
                                     (__attribute__((address_space(3))) void*)l, 16, 0, 0);
}

// read the 16 fragments of one K-tile (swizzled chunk addressing, matches STAGE)
#define READ_FRAGS(aF, bF, sa, sb)                                              \
  _Pragma("unroll")                                                             \
  for (int m = 0; m < 4; ++m) {                                                 \
    const int r = wm * 64 + m * 16 + lrow;                                      \
    _Pragma("unroll")                                                           \
    for (int kk = 0; kk < 2; ++kk) {                                            \
      const int c = (kk * 4 + lk) ^ (r & 7);                                    \
      aF[m][kk] = *(const mfrag*)((sa) + (size_t)r * 128 + c * 16);             \
    }                                                                           \
  }                                                                             \
  _Pragma("unroll")                                                             \
  for (int n = 0; n < 4; ++n) {                                                 \
    const int r = wn * 64 + n * 16 + lrow;                                      \
    _Pragma("unroll")                                                           \
    for (int kk = 0; kk < 2; ++kk) {                                            \
      const int c = (kk * 4 + lk) ^ (r & 7);                                    \
      bF[n][kk] = *(const mfrag*)((sb) + (size_t)r * 128 + c * 16);             \
    }                                                                           \
  }

#define MFMA_ALL(aF, bF)                                                        \
  __builtin_amdgcn_s_setprio(1);                                                \
  _Pragma("unroll")                                                             \
  for (int m = 0; m < 4; ++m)                                                   \
    _Pragma("unroll")                                                           \
    for (int n = 0; n < 4; ++n) {                                               \
      acc[m][n] = __builtin_amdgcn_mfma_f32_16x16x32_bf16(aF[m][0], bF[n][0], acc[m][n], 0, 0, 0); \
      acc[m][n] = __builtin_amdgcn_mfma_f32_16x16x32_bf16(aF[m][1], bF[n][1], acc[m][n], 0, 0, 0); \
    }                                                                           \
  __builtin_amdgcn_s_setprio(0);

// ---------------------------------------------------------------- pipelined GEMM
// A: (M,K) bf16 row-major; Bt: (N,K) bf16 row-major (B^T). C: (M,N) bf16 or f32.
// 256x128 tile, BK=64, 8 waves (4x2), 2-slot LDS ring, stage depth 2,
// fragment double-buffer so ds_read(t+1) overlaps MFMA(t). NT must be even.
__global__ __launch_bounds__(512, 2) void k_gemm_p(const bf16* __restrict__ A,
                                                   const bf16* __restrict__ Bt,
                                                   void* __restrict__ Cv,
                                                   int M, int N, int K, int obf) {
    extern __shared__ char smem[];
    const int tid  = threadIdx.x;
    const int wave = tid >> 6;
    const int lane = tid & 63;
    const int lrow = lane & 15;
    const int lk   = lane >> 4;
    const int wm   = wave >> 1;          // 0..3 (row block of 64)
    const int wn   = wave & 1;           // 0..1 (col block of 64)

    // XCD-aware bijective swizzle (grid sizes here are multiples of 8)
    const int nbn = N >> 7;
    const int nwg = gridDim.x;
    const int cpx = nwg >> 3;
    const int bid = blockIdx.x;
    const int swz = (bid & 7) * cpx + (bid >> 3);
    const int bm  = (swz / nbn) << 8;
    const int bn  = (swz % nbn) << 7;

    const int NT = K >> 6;

    char* slot0 = smem;
    char* slot1 = smem + SLOT_BYTES;

    auto STAGE = [&](int t, char* sbase) {
        const int koff = t << 6;
#pragma unroll
        for (int i = 0; i < 4; ++i) {            // A: 256 rows x 8 chunks
            const int L   = i * 512 + tid;
            const int row = L >> 3;
            const int cl  = (L & 7) ^ (row & 7); // pre-swizzled source chunk
            const bf16* g = A + (size_t)(bm + row) * K + koff + cl * 8;
            bf16* l = (bf16*)(sbase + (size_t)(i * 512 + wave * 64) * 16);
            gld_lds16(g, l);
        }
#pragma unroll
        for (int i = 0; i < 2; ++i) {            // B: 128 rows x 8 chunks
            const int L   = i * 512 + tid;
            const int row = L >> 3;
            const int cl  = (L & 7) ^ (row & 7);
            const bf16* g = Bt + (size_t)(bn + row) * K + koff + cl * 8;
            bf16* l = (bf16*)(sbase + SLOT_A_BYTES + (size_t)(i * 512 + wave * 64) * 16);
            gld_lds16(g, l);
        }
    };

    f32x4 acc[4][4];
#pragma unroll
    for (int m = 0; m < 4; ++m)
#pragma unroll
        for (int n = 0; n < 4; ++n) acc[m][n] = f32x4{0.f, 0.f, 0.f, 0.f};

    mfrag aE[4][2], bE[4][2], aO[4][2], bO[4][2];

    // prologue: stage tiles 0,1; wait tile 0; read its fragments
    STAGE(0, slot0);
    STAGE(1, slot1);
    asm volatile("s_waitcnt vmcnt(6)" ::: "memory");
    __builtin_amdgcn_sched_barrier(0);
    __builtin_amdgcn_s_barrier();
    READ_FRAGS(aE, bE, slot0, slot0 + SLOT_A_BYTES);

    for (int t = 0; t < NT; t += 2) {
        // ---- half A: compute tile t (fragsE); stage t+2 -> slot0; read t+1 -> fragsO
        asm volatile("s_waitcnt lgkmcnt(0)" ::: "memory");   // fragsE in regs
        __builtin_amdgcn_sched_barrier(0);
        __builtin_amdgcn_s_barrier();                        // all waves done with slot0
        if (t + 2 < NT) {
            STAGE(t + 2, slot0);
            asm volatile("s_waitcnt vmcnt(6)" ::: "memory"); // tile t+1 landed
        } else {
            asm volatile("s_waitcnt vmcnt(0)" ::: "memory");
        }
        __builtin_amdgcn_sched_barrier(0);
        __builtin_amdgcn_s_barrier();                        // landed block-wide
        READ_FRAGS(aO, bO, slot1, slot1 + SLOT_A_BYTES);     // tile t+1
        __builtin_amdgcn_sched_barrier(0);
        MFMA_ALL(aE, bE);                                    // overlaps the ds_reads

        // ---- half B: compute tile t+1 (fragsO); stage t+3 -> slot1; read t+2 -> fragsE
        asm volatile("s_waitcnt lgkmcnt(0)" ::: "memory");   // fragsO in regs
        __builtin_amdgcn_sched_barrier(0);
        __builtin_amdgcn_s_barrier();                        // all waves done with slot1
        if (t + 2 < NT) {
            if (t + 3 < NT) {
                STAGE(t + 3, slot1);
                asm volatile("s_waitcnt vmcnt(6)" ::: "memory"); // tile t+2 landed
            } else {
                asm volatile("s_waitcnt vmcnt(0)" ::: "memory");
            }
            __builtin_amdgcn_sched_barrier(0);
            __builtin_amdgcn_s_barrier();
            READ_FRAGS(aE, bE, slot0, slot0 + SLOT_A_BYTES); // tile t+2
            __builtin_amdgcn_sched_barrier(0);
        }
        MFMA_ALL(aO, bO);
    }

    // ---- epilogue
#pragma unroll
    for (int m = 0; m < 4; ++m)
#pragma unroll
        for (int j = 0; j < 4; ++j) {
            const int r = bm + wm * 64 + m * 16 + lk * 4 + j;
#pragma unroll
            for (int n = 0; n < 4; ++n) {
                const int c = bn + wn * 64 + n * 16 + lrow;
                if (obf) ((bf16*)Cv)[(size_t)r * N + c] = __float2bfloat16(acc[m][n][j]);
                else     ((float*)Cv)[(size_t)r * N + c] = acc[m][n][j];
            }
        }
}

// ---------------------------------------------------------------- f32 -> bf16 cast
__global__ void k_cast_bf16(const float* __restrict__ in, bf16* __restrict__ out, int n) {
    int i = (blockIdx.x * 256 + threadIdx.x) * 4;
    if (i >= n) return;
    float4 v = *(const float4*)(in + i);
    out[i + 0] = __float2bfloat16(v.x);
    out[i + 1] = __float2bfloat16(v.y);
    out[i + 2] = __float2bfloat16(v.z);
    out[i + 3] = __float2bfloat16(v.w);
}

// ---------------------------------------------------------------- fused weight build:
// Wt[n][k] (9216 x 2048 bf16) = selected column col(n) of Wq/Wk(even)/Wv/Wg.
__global__ void k_prep_w(const float* __restrict__ Wq, const float* __restrict__ Wk,
                         const float* __restrict__ Wv, const float* __restrict__ Wg,
                         bf16* __restrict__ Wt) {
    __shared__ float t[32][33];
    const int n0 = blockIdx.x * 32;
    const int k0 = blockIdx.y * 32;
    const int tx = threadIdx.x, ty = threadIdx.y;
    const float* src; int cb, cs;
    if (n0 < 1536)      { int m = n0;        src = Wq; cb = (m >> 8) * 512 + (m & 255) * 2; cs = 2; }
    else if (n0 < 3072) { int m = n0 - 1536; src = Wk; cb = (m >> 8) * 512 + (m & 255) * 2; cs = 2; }
    else if (n0 < 6144) { int m = n0 - 3072; src = Wv; cb = m; cs = 1; }
    else                { int m = n0 - 6144; src = Wg; cb = m; cs = 1; }
#pragma unroll
    for (int i = 0; i < 4; ++i) {
        int k = k0 + ty + i * 8;
        t[ty + i * 8][tx] = src[(size_t)k * VD + cb + cs * tx];
    }
    __syncthreads();
#pragma unroll
    for (int i = 0; i < 4; ++i) {
        int n = n0 + ty + i * 8;
        Wt[(size_t)n * HID + k0 + tx] = __float2bfloat16(t[tx][ty + i * 8]);
    }
}

// ---------------------------------------------------------------- transpose+cast: dst[c][r] = src[r][c]
__global__ void k_tr_cast(const float* __restrict__ src, bf16* __restrict__ dst, int R, int Ccol) {
    __shared__ float t[32][33];
    const int c0 = blockIdx.x * 32, r0 = blockIdx.y * 32;
    const int tx = threadIdx.x, ty = threadIdx.y;
#pragma unroll
    for (int i = 0; i < 4; ++i)
        t[ty + i * 8][tx] = src[(size_t)(r0 + ty + i * 8) * Ccol + c0 + tx];
    __syncthreads();
#pragma unroll
    for (int i = 0; i < 4; ++i)
        dst[(size_t)(c0 + ty + i * 8) * R + r0 + tx] = __float2bfloat16(t[tx][ty + i * 8]);
}

// ---------------------------------------------------------------- alpha/beta (tiny GEMM + sigmoid)
__global__ __launch_bounds__(256) void k_ab(const float* __restrict__ hs, const float* __restrict__ Wa,
                                            const float* __restrict__ Wb,
                                            float* __restrict__ alpha, float* __restrict__ beta) {
    const int tok = blockIdx.x;
    const int tid = threadIdx.x;
    float part[12];
#pragma unroll
    for (int j = 0; j < 12; ++j) part[j] = 0.f;
    const float* hrow = hs + (size_t)tok * HID;
    for (int i = 0; i < 8; ++i) {
        int k = i * 256 + tid;
        float x = hrow[k];
        const float* wa = Wa + k * NH;
        const float* wb = Wb + k * NH;
#pragma unroll
        for (int j = 0; j < NH; ++j) {
            part[j]     = fmaf(x, wa[j], part[j]);
            part[6 + j] = fmaf(x, wb[j], part[6 + j]);
        }
    }
    __shared__ float red[12][4];
    const int lane = tid & 63, wv = tid >> 6;
#pragma unroll
    for (int j = 0; j < 12; ++j) {
        float s = part[j];
        for (int off = 32; off; off >>= 1) s += __shfl_down(s, off);
        if (lane == 0) red[j][wv] = s;
    }
    __syncthreads();
    if (tid < 12) {
        float s = red[tid][0] + red[tid][1] + red[tid][2] + red[tid][3];
        float v = 1.f / (1.f + expf(-s));
        if (tid < 6) alpha[(size_t)tok * NH + tid] = v;
        else         beta [(size_t)tok * NH + tid - 6] = v;
    }
}

// ---------------------------------------------------------------- conv + phase + rotate + local chunk scan
__global__ __launch_bounds__(256) void k_scan1(const bf16* __restrict__ X,
                                               const float* __restrict__ alpha,
                                               const float* __restrict__ beta,
                                               const float* __restrict__ cq,
                                               const float* __restrict__ ck,
                                               const float* __restrict__ cv,
                                               float* __restrict__ U, float* __restrict__ pp) {
    const int bx = blockIdx.x;
    const int c  = bx % NC;
    const int h  = (bx / NC) % NH;
    const int b  = bx / (NC * NH);
    const int p  = threadIdx.x;
    const int t0 = c * CHUNK;
    const int ch2 = h * HD + 2 * p;
    const float wq0 = cq[ch2 * 4 + 0], wq1 = cq[ch2 * 4 + 1], wq2 = cq[ch2 * 4 + 2], wq3 = cq[ch2 * 4 + 3];
    const float wk0 = ck[ch2 * 4 + 0], wk1 = ck[ch2 * 4 + 1], wk2 = ck[ch2 * 4 + 2], wk3 = ck[ch2 * 4 + 3];
    const float wa0 = cv[ch2 * 4 + 0], wa1 = cv[ch2 * 4 + 1], wa2 = cv[ch2 * 4 + 2], wa3 = cv[ch2 * 4 + 3];
    const float wb0 = cv[(ch2 + 1) * 4 + 0], wb1 = cv[(ch2 + 1) * 4 + 1],
                wb2 = cv[(ch2 + 1) * 4 + 2], wb3 = cv[(ch2 + 1) * 4 + 3];
    const float invf = exp2f(-13.287712379549449f * ((float)p * (1.0f / 256.0f)));
    const int qcol = h * NPAIR + p;
    const int kcol = 1536 + h * NPAIR + p;
    const int vcol = 3072 + ch2;

    float xq[3], xk[3], xv0[3], xv1[3];
#pragma unroll
    for (int i = 0; i < 3; ++i) {
        int t = t0 - 3 + i;
        if (t >= 0) {
            size_t tok = (size_t)b * 2048 + t;
            const bf16* xr = X + tok * N1;
            xq[i] = __bfloat162float(xr[qcol]);
            xk[i] = __bfloat162float(xr[kcol]);
            __hip_bfloat162 vv = *(const __hip_bfloat162*)&xr[vcol];
            xv0[i] = __bfloat162float(vv.x);
            xv1[i] = __bfloat162float(vv.y);
        } else { xq[i] = xk[i] = xv0[i] = xv1[i] = 0.f; }
    }

    float u0 = 0.f, u1 = 0.f, ap = 1.f;
    for (int t = t0; t < t0 + CHUNK; ++t) {
        const size_t tok = (size_t)b * 2048 + t;
        const bf16* xr = X + tok * N1;
        float nq = __bfloat162float(xr[qcol]);
        float nk = __bfloat162float(xr[kcol]);
        __hip_bfloat162 vv = *(const __hip_bfloat162*)&xr[vcol];
        float nv0 = __bfloat162float(vv.x);
        float nv1 = __bfloat162float(vv.y);
        float yq  = wq3 * nq  + wq2 * xq[2]  + wq1 * xq[1]  + wq0 * xq[0];
        float yk  = wk3 * nk  + wk2 * xk[2]  + wk1 * xk[1]  + wk0 * xk[0];
        float yv0 = wa3 * nv0 + wa2 * xv0[2] + wa1 * xv0[1] + wa0 * xv0[0];
        float yv1 = wb3 * nv1 + wb2 * xv1[2] + wb1 * xv1[1] + wb0 * xv1[0];
        xq[0] = xq[1]; xq[1] = xq[2]; xq[2] = nq;
        xk[0] = xk[1]; xk[1] = xk[2]; xk[2] = nk;
        xv0[0] = xv0[1]; xv0[1] = xv0[2]; xv0[2] = nv0;
        xv1[0] = xv1[1]; xv1[1] = xv1[2]; xv1[2] = nv1;
        float theta = yq * invf, psi = yk * invf;
        float d = psi - theta, sn, cs;
        __sincosf(d, &sn, &cs);
        float w0 = yv0 * cs - yv1 * sn;
        float w1 = yv1 * cs + yv0 * sn;
        float a  = alpha[tok * NH + h];
        float bb = beta [tok * NH + h];
        u0 = fmaf(a, u0, bb * w0);
        u1 = fmaf(a, u1, bb * w1);
        ap *= a;
        *(float2*)&U[tok * (size_t)VD + h * HD + 2 * p] = float2{u0, u1};
        if (p == 0) pp[tok * NH + h] = ap;
    }
}

// ---------------------------------------------------------------- cross-chunk carry
__global__ void k_carry(const float* __restrict__ U, const float* __restrict__ pp,
                        float* __restrict__ carry) {
    const int bh = blockIdx.x;              // 0..11 = b*NH+h
    const int b = bh / NH, h = bh % NH;
    const int tid = threadIdx.x;
    for (int half = 0; half < 2; ++half) {
        const int d = tid + half * 256;
        float s = 0.f;
        for (int c = 0; c < NC; ++c) {
            carry[((size_t)bh * NC + c) * HD + d] = s;
            int tend = c * CHUNK + CHUNK - 1;
            size_t tok = (size_t)b * 2048 + tend;
            s = U[tok * (size_t)VD + h * HD + d] + pp[tok * NH + h] * s;
        }
    }
}

// ---------------------------------------------------------------- carry fix + RMS + SiLU gate -> bf16 O
__global__ __launch_bounds__(256) void k_pass3(const float* __restrict__ U, const float* __restrict__ pp,
                                               const float* __restrict__ carry, const bf16* __restrict__ X,
                                               const float* __restrict__ rms_w, bf16* __restrict__ O) {
    const int bx = blockIdx.x;              // tok*NH + h
    const int h = bx % NH;
    const size_t tok = bx / NH;
    const int b = (int)(tok >> 11);
    const int t = (int)(tok & 2047);
    const int c = t / CHUNK;
    const int tid = threadIdx.x;
    const int d = tid * 2;
    float2 uu = *(const float2*)&U[tok * (size_t)VD + h * HD + d];
    float  P  = pp[tok * NH + h];
    float2 cy = *(const float2*)&carry[((size_t)(b * NH + h) * NC + c) * HD + d];
    float u0 = fmaf(P, cy.x, uu.x);
    float u1 = fmaf(P, cy.y, uu.y);
    float s = u0 * u0 + u1 * u1;
    for (int off = 32; off; off >>= 1) s += __shfl_down(s, off);
    __shared__ float r4[4];
    const int lane = tid & 63, wv = tid >> 6;
    if (lane == 0) r4[wv] = s;
    __syncthreads();
    float tot = r4[0] + r4[1] + r4[2] + r4[3];
    float rms = rsqrtf(tot * (1.f / 512.f) + 1e-5f);
    __hip_bfloat162 gg = *(const __hip_bfloat162*)&X[tok * N1 + 6144 + h * HD + d];
    float g0 = __bfloat162float(gg.x), g1 = __bfloat162float(gg.y);
    float si0 = g0 / (1.f + expf(-g0));
    float si1 = g1 / (1.f + expf(-g1));
    float o0 = u0 * rms * rms_w[d]     * si0;
    float o1 = u1 * rms * rms_w[d + 1] * si1;
    __hip_bfloat162 ob;
    ob.x = __float2bfloat16(o0);
    ob.y = __float2bfloat16(o1);
    *(__hip_bfloat162*)&O[tok * (size_t)VD + h * HD + d] = ob;
}

// ----------------------------------------------------------------
extern "C" void kernel_launch(void* const* d_in, const int* in_sizes, int n_in,
                              void* d_out, int out_size, void* d_ws, size_t ws_size,
                              hipStream_t stream) {
    const float* hs   = (const float*)d_in[0];
    const float* Wq   = (const float*)d_in[1];
    const float* Wk   = (const float*)d_in[2];
    const float* Wv   = (const float*)d_in[3];
    const float* Wa   = (const float*)d_in[4];
    const float* Wb   = (const float*)d_in[5];
    const float* Wg   = (const float*)d_in[6];
    const float* Wo   = (const float*)d_in[7];
    const float* cq   = (const float*)d_in[8];
    const float* ck   = (const float*)d_in[9];
    const float* cv   = (const float*)d_in[10];
    const float* rmsw = (const float*)d_in[11];

    char* ws = (char*)d_ws;
    size_t off = 0;
    auto alloc = [&](size_t bytes) -> void* {
        void* p = ws + off;
        off = (off + bytes + 255) & ~(size_t)255;
        return p;
    };
    bf16*  hsb   = (bf16*) alloc((size_t)TOKENS * HID * 2);       // 16.8 MB
    bf16*  Wt    = (bf16*) alloc((size_t)N1 * HID * 2);           // 37.7 MB
    bf16*  Wot   = (bf16*) alloc((size_t)HID * VD * 2);           // 12.6 MB
    bf16*  X     = (bf16*) alloc((size_t)TOKENS * N1 * 2);        // 75.5 MB
    float* U     = (float*)alloc((size_t)TOKENS * VD * 4);        // 50.3 MB
    float* alp   = (float*)alloc((size_t)TOKENS * NH * 4);
    float* bet   = (float*)alloc((size_t)TOKENS * NH * 4);
    float* pp    = (float*)alloc((size_t)TOKENS * NH * 4);
    float* carry = (float*)alloc((size_t)2 * NH * NC * HD * 4);
    bf16*  O     = (bf16*)Wt;   // alias: Wt dead after GEMM-1, O written after

    hipFuncSetAttribute((const void*)k_gemm_p,
                        hipFuncAttributeMaxDynamicSharedMemorySize, SMEM_BYTES);

    k_cast_bf16<<<TOKENS * HID / 1024, 256, 0, stream>>>(hs, hsb, TOKENS * HID);
    k_prep_w<<<dim3(N1 / 32, HID / 32), dim3(32, 8), 0, stream>>>(Wq, Wk, Wv, Wg, Wt);
    k_tr_cast<<<dim3(HID / 32, VD / 32), dim3(32, 8), 0, stream>>>(Wo, Wot, VD, HID);
    k_ab<<<TOKENS, 256, 0, stream>>>(hs, Wa, Wb, alp, bet);
    // X = hsb @ Wt^T   (M=4096, N=9216, K=2048) -> 16*72 = 1152 blocks
    k_gemm_p<<<dim3((TOKENS / BM) * (N1 / BN)), 512, SMEM_BYTES, stream>>>(hsb, Wt, X, TOKENS, N1, HID, 1);
    k_scan1<<<2 * NH * NC, 256, 0, stream>>>(X, alp, bet, cq, ck, cv, U, pp);
    k_carry<<<2 * NH, 256, 0, stream>>>(U, pp, carry);
    k_pass3<<<TOKENS * NH, 256, 0, stream>>>(U, pp, carry, X, rmsw, O);
    // out = O @ Wot^T  (M=4096, N=2048, K=3072) -> 16*16 = 256 blocks, f32 out
    k_gemm_p<<<dim3((TOKENS / BM) * (HID / BN)), 512, SMEM_BYTES, stream>>>(O, Wot, d_out, TOKENS, HID, VD, 0);
}

// Round 7
// 399.045 us; speedup vs baseline: 11.5944x; 1.0126x over previous
//
#include <hip/hip_runtime.h>
#include <hip/hip_bf16.h>
#include <stdint.h>

using bf16 = __hip_bfloat16;
using mfrag = __attribute__((ext_vector_type(8))) __bf16;   // 8 bf16 = 4 VGPRs
using f32x4 = __attribute__((ext_vector_type(4))) float;

#define TOKENS 4096
#define HID    2048
#define VD     3072
#define NH     6
#define HD     512
#define NPAIR  256
#define N1     9216     /* q_even(1536) | k_even(1536) | v(3072) | g(3072) */
#define NC     64
#define CHUNK  32

__device__ __forceinline__ void gld_lds16(const bf16* g, bf16* l) {
    __builtin_amdgcn_global_load_lds((const __attribute__((address_space(1))) void*)g,
                                     (__attribute__((address_space(3))) void*)l, 16, 0, 0);
}

// ================================================================ 8-phase 256x256 GEMM (m201 structure)
// A: (M,K) bf16 row-major; Bt: (N,K) bf16 row-major (B^T). C: (M,N) bf16 or f32.
// 512 threads = 8 waves (2M x 4N), per-wave output 128x64, BK=64.
// LDS: 2 buffers x 4 half-tiles (A0,A1,B0,B1) x 16 KiB = 128 KiB.
// Per K-step: 4 phases {ds_read subtile; stage 1-2 half-tiles; bar; lgkm(0); 16 MFMA; [vmcnt(0)]; bar}.
#define G8_HT    16384                 /* 128 x 64 x 2B half-tile */
#define G8_SLOT  (4 * G8_HT)           /* 64 KiB per buffer */
#define G8_SMEM  (2 * G8_SLOT)         /* 128 KiB */

__global__ __launch_bounds__(512, 2) void k_gemm8(const bf16* __restrict__ A,
                                                  const bf16* __restrict__ Bt,
                                                  void* __restrict__ Cv,
                                                  int M, int N, int K, int obf) {
    extern __shared__ char smem[];
    const int tid  = threadIdx.x;
    const int wave = tid >> 6;
    const int lane = tid & 63;
    const int lrow = lane & 15;
    const int lk   = lane >> 4;
    const int wm   = wave >> 2;          // 0..1 : row half (128 rows)
    const int wn   = wave & 3;           // 0..3 : col quarter (64 cols)

    // XCD-aware bijective swizzle (grid %8 == 0 here)
    const int nbn = N >> 8;
    const int cpx = gridDim.x >> 3;
    const int bid = blockIdx.x;
    const int swz = (bid & 7) * cpx + (bid >> 3);
    const int bm  = (swz / nbn) << 8;
    const int bn  = (swz % nbn) << 8;

    const int NT = K >> 6;

    // stage one 128x64 half-tile (2 gld_lds per thread); dest linear, source chunk pre-swizzled
    auto stage_ht = [&](const bf16* src, int row0, char* htbase, int koff) {
#pragma unroll
        for (int i = 0; i < 2; ++i) {
            const int L = i * 512 + tid;
            const int r = L >> 3;
            const int c = (L & 7) ^ (r & 7);
            gld_lds16(src + (size_t)(row0 + r) * K + koff + c * 8,
                      (bf16*)(htbase + (size_t)L * 16));
        }
    };

    f32x4 acc[8][4];
#pragma unroll
    for (int m = 0; m < 8; ++m)
#pragma unroll
        for (int n = 0; n < 4; ++n) acc[m][n] = f32x4{0.f, 0.f, 0.f, 0.f};

    // prologue: stage K-step 0 into buf0, drain, barrier
    {
        char* wb = smem;
        stage_ht(A,  bm,        wb + 0 * G8_HT, 0);
        stage_ht(A,  bm + 128,  wb + 1 * G8_HT, 0);
        stage_ht(Bt, bn,        wb + 2 * G8_HT, 0);
        stage_ht(Bt, bn + 128,  wb + 3 * G8_HT, 0);
        asm volatile("s_waitcnt vmcnt(0)" ::: "memory");
        __builtin_amdgcn_sched_barrier(0);
        __builtin_amdgcn_s_barrier();
    }

    for (int kt = 0; kt < NT; ++kt) {
        char* rb = smem + (size_t)(kt & 1) * G8_SLOT;
        char* wb = smem + (size_t)((kt + 1) & 1) * G8_SLOT;
        const int koff2 = (kt + 1) << 6;
        const bool do_stage = (kt + 1 < NT);

        mfrag bfr[4][2];
#pragma unroll
        for (int q = 0; q < 4; ++q) {
            // ---- ds-read register subtile (phase 0: B(8) + A-quad0(4); else A-quad(4))
            if (q == 0) {
#pragma unroll
                for (int nf = 0; nf < 4; ++nf) {
                    const int ch = (wn & 1) * 64 + nf * 16 + lrow;
#pragma unroll
                    for (int kk = 0; kk < 2; ++kk) {
                        const int cc = (kk * 4 + lk) ^ (ch & 7);
                        bfr[nf][kk] = *(const mfrag*)(rb + (2 + (wn >> 1)) * G8_HT + (size_t)ch * 128 + cc * 16);
                    }
                }
            }
            mfrag af[2][2];
#pragma unroll
            for (int mf = 0; mf < 2; ++mf) {
                const int rh = q * 32 + mf * 16 + lrow;
#pragma unroll
                for (int kk = 0; kk < 2; ++kk) {
                    const int cc = (kk * 4 + lk) ^ (rh & 7);
                    af[mf][kk] = *(const mfrag*)(rb + wm * G8_HT + (size_t)rh * 128 + cc * 16);
                }
            }
            // ---- stage next K-step's half-tiles (2 at phase 0, 1 at phases 1-2)
            if (do_stage) {
                if (q == 0) { stage_ht(A,  bm,       wb + 0 * G8_HT, koff2);
                              stage_ht(A,  bm + 128, wb + 1 * G8_HT, koff2); }
                if (q == 1)   stage_ht(Bt, bn,       wb + 2 * G8_HT, koff2);
                if (q == 2)   stage_ht(Bt, bn + 128, wb + 3 * G8_HT, koff2);
            }
            __builtin_amdgcn_sched_barrier(0);
            __builtin_amdgcn_s_barrier();
            asm volatile("s_waitcnt lgkmcnt(0)" ::: "memory");
            __builtin_amdgcn_sched_barrier(0);
            // ---- 16 MFMA (one 32-row quadrant x K=64)
            __builtin_amdgcn_s_setprio(1);
#pragma unroll
            for (int mf = 0; mf < 2; ++mf)
#pragma unroll
                for (int nf = 0; nf < 4; ++nf) {
                    acc[q * 2 + mf][nf] = __builtin_amdgcn_mfma_f32_16x16x32_bf16(af[mf][0], bfr[nf][0], acc[q * 2 + mf][nf], 0, 0, 0);
                    acc[q * 2 + mf][nf] = __builtin_amdgcn_mfma_f32_16x16x32_bf16(af[mf][1], bfr[nf][1], acc[q * 2 + mf][nf], 0, 0, 0);
                }
            __builtin_amdgcn_s_setprio(0);
            // ---- last phase of K-step: own stage loads landed BEFORE closing barrier
            if (q == 3 && do_stage) {
                asm volatile("s_waitcnt vmcnt(0)" ::: "memory");
            }
            __builtin_amdgcn_sched_barrier(0);
            __builtin_amdgcn_s_barrier();
        }
    }

    // ---- epilogue
#pragma unroll
    for (int m = 0; m < 8; ++m)
#pragma unroll
        for (int j = 0; j < 4; ++j) {
            const int r = bm + wm * 128 + m * 16 + lk * 4 + j;
#pragma unroll
            for (int n = 0; n < 4; ++n) {
                const int c = bn + wn * 64 + n * 16 + lrow;
                if (obf) ((bf16*)Cv)[(size_t)r * N + c] = __float2bfloat16(acc[m][n][j]);
                else     ((float*)Cv)[(size_t)r * N + c] = acc[m][n][j];
            }
        }
}

// ================================================================ 256x128 pipelined GEMM (round-6, kept for GEMM-2)
#define BM    256
#define BN    128
#define BK    64
#define SLOT_A_BYTES (BM * BK * 2)                 /* 32768 */
#define SLOT_BYTES   (SLOT_A_BYTES + BN * BK * 2)  /* 49152 */
#define SMEM_BYTES   (2 * SLOT_BYTES)              /* 98304 */

#define READ_FRAGS(aF, bF, sa, sb)                                              \
  _Pragma("unroll")                                                             \
  for (int m = 0; m < 4; ++m) {                                                 \
    const int r = wm * 64 + m * 16 + lrow;                                      \
    _Pragma("unroll")                                                           \
    for (int kk = 0; kk < 2; ++kk) {                                            \
      const int c = (kk * 4 + lk) ^ (r & 7);                                    \
      aF[m][kk] = *(const mfrag*)((sa) + (size_t)r * 128 + c * 16);             \
    }                                                                           \
  }                                                                             \
  _Pragma("unroll")                                                             \
  for (int n = 0; n < 4; ++n) {                                                 \
    const int r = wn * 64 + n * 16 + lrow;                                      \
    _Pragma("unroll")                                                           \
    for (int kk = 0; kk < 2; ++kk) {                                            \
      const int c = (kk * 4 + lk) ^ (r & 7);                                    \
      bF[n][kk] = *(const mfrag*)((sb) + (size_t)r * 128 + c * 16);             \
    }                                                                           \
  }

#define MFMA_ALL(aF, bF)                                                        \
  __builtin_amdgcn_s_setprio(1);                                                \
  _Pragma("unroll")                                                             \
  for (int m = 0; m < 4; ++m)                                                   \
    _Pragma("unroll")                                                           \
    for (int n = 0; n < 4; ++n) {                                               \
      acc[m][n] = __builtin_amdgcn_mfma_f32_16x16x32_bf16(aF[m][0], bF[n][0], acc[m][n], 0, 0, 0); \
      acc[m][n] = __builtin_amdgcn_mfma_f32_16x16x32_bf16(aF[m][1], bF[n][1], acc[m][n], 0, 0, 0); \
    }                                                                           \
  __builtin_amdgcn_s_setprio(0);

__global__ __launch_bounds__(512, 2) void k_gemm_p(const bf16* __restrict__ A,
                                                   const bf16* __restrict__ Bt,
                                                   void* __restrict__ Cv,
                                                   int M, int N, int K, int obf) {
    extern __shared__ char smem[];
    const int tid  = threadIdx.x;
    const int wave = tid >> 6;
    const int lane = tid & 63;
    const int lrow = lane & 15;
    const int lk   = lane >> 4;
    const int wm   = wave >> 1;
    const int wn   = wave & 1;

    const int nbn = N >> 7;
    const int cpx = gridDim.x >> 3;
    const int bid = blockIdx.x;
    const int swz = (bid & 7) * cpx + (bid >> 3);
    const int bm  = (swz / nbn) << 8;
    const int bn  = (swz % nbn) << 7;

    const int NT = K >> 6;

    char* slot0 = smem;
    char* slot1 = smem + SLOT_BYTES;

    auto STAGE = [&](int t, char* sbase) {
        const int koff = t << 6;
#pragma unroll
        for (int i = 0; i < 4; ++i) {
            const int L   = i * 512 + tid;
            const int row = L >> 3;
            const int cl  = (L & 7) ^ (row & 7);
            const bf16* g = A + (size_t)(bm + row) * K + koff + cl * 8;
            bf16* l = (bf16*)(sbase + (size_t)(i * 512 + wave * 64) * 16);
            gld_lds16(g, l);
        }
#pragma unroll
        for (int i = 0; i < 2; ++i) {
            const int L   = i * 512 + tid;
            const int row = L >> 3;
            const int cl  = (L & 7) ^ (row & 7);
            const bf16* g = Bt + (size_t)(bn + row) * K + koff + cl * 8;
            bf16* l = (bf16*)(sbase + SLOT_A_BYTES + (size_t)(i * 512 + wave * 64) * 16);
            gld_lds16(g, l);
        }
    };

    f32x4 acc[4][4];
#pragma unroll
    for (int m = 0; m < 4; ++m)
#pragma unroll
        for (int n = 0; n < 4; ++n) acc[m][n] = f32x4{0.f, 0.f, 0.f, 0.f};

    mfrag aE[4][2], bE[4][2], aO[4][2], bO[4][2];

    STAGE(0, slot0);
    STAGE(1, slot1);
    asm volatile("s_waitcnt vmcnt(6)" ::: "memory");
    __builtin_amdgcn_sched_barrier(0);
    __builtin_amdgcn_s_barrier();
    READ_FRAGS(aE, bE, slot0, slot0 + SLOT_A_BYTES);

    for (int t = 0; t < NT; t += 2) {
        asm volatile("s_waitcnt lgkmcnt(0)" ::: "memory");
        __builtin_amdgcn_sched_barrier(0);
        __builtin_amdgcn_s_barrier();
        if (t + 2 < NT) {
            STAGE(t + 2, slot0);
            asm volatile("s_waitcnt vmcnt(6)" ::: "memory");
        } else {
            asm volatile("s_waitcnt vmcnt(0)" ::: "memory");
        }
        __builtin_amdgcn_sched_barrier(0);
        __builtin_amdgcn_s_barrier();
        READ_FRAGS(aO, bO, slot1, slot1 + SLOT_A_BYTES);
        __builtin_amdgcn_sched_barrier(0);
        MFMA_ALL(aE, bE);

        asm volatile("s_waitcnt lgkmcnt(0)" ::: "memory");
        __builtin_amdgcn_sched_barrier(0);
        __builtin_amdgcn_s_barrier();
        if (t + 2 < NT) {
            if (t + 3 < NT) {
                STAGE(t + 3, slot1);
                asm volatile("s_waitcnt vmcnt(6)" ::: "memory");
            } else {
                asm volatile("s_waitcnt vmcnt(0)" ::: "memory");
            }
            __builtin_amdgcn_sched_barrier(0);
            __builtin_amdgcn_s_barrier();
            READ_FRAGS(aE, bE, slot0, slot0 + SLOT_A_BYTES);
            __builtin_amdgcn_sched_barrier(0);
        }
        MFMA_ALL(aO, bO);
    }

#pragma unroll
    for (int m = 0; m < 4; ++m)
#pragma unroll
        for (int j = 0; j < 4; ++j) {
            const int r = bm + wm * 64 + m * 16 + lk * 4 + j;
#pragma unroll
            for (int n = 0; n < 4; ++n) {
                const int c = bn + wn * 64 + n * 16 + lrow;
                if (obf) ((bf16*)Cv)[(size_t)r * N + c] = __float2bfloat16(acc[m][n][j]);
                else     ((float*)Cv)[(size_t)r * N + c] = acc[m][n][j];
            }
        }
}

// ---------------------------------------------------------------- f32 -> bf16 cast
__global__ void k_cast_bf16(const float* __restrict__ in, bf16* __restrict__ out, int n) {
    int i = (blockIdx.x * 256 + threadIdx.x) * 4;
    if (i >= n) return;
    float4 v = *(const float4*)(in + i);
    out[i + 0] = __float2bfloat16(v.x);
    out[i + 1] = __float2bfloat16(v.y);
    out[i + 2] = __float2bfloat16(v.z);
    out[i + 3] = __float2bfloat16(v.w);
}

// ---------------------------------------------------------------- fused weight build
__global__ void k_prep_w(const float* __restrict__ Wq, const float* __restrict__ Wk,
                         const float* __restrict__ Wv, const float* __restrict__ Wg,
                         bf16* __restrict__ Wt) {
    __shared__ float t[32][33];
    const int n0 = blockIdx.x * 32;
    const int k0 = blockIdx.y * 32;
    const int tx = threadIdx.x, ty = threadIdx.y;
    const float* src; int cb, cs;
    if (n0 < 1536)      { int m = n0;        src = Wq; cb = (m >> 8) * 512 + (m & 255) * 2; cs = 2; }
    else if (n0 < 3072) { int m = n0 - 1536; src = Wk; cb = (m >> 8) * 512 + (m & 255) * 2; cs = 2; }
    else if (n0 < 6144) { int m = n0 - 3072; src = Wv; cb = m; cs = 1; }
    else                { int m = n0 - 6144; src = Wg; cb = m; cs = 1; }
#pragma unroll
    for (int i = 0; i < 4; ++i) {
        int k = k0 + ty + i * 8;
        t[ty + i * 8][tx] = src[(size_t)k * VD + cb + cs * tx];
    }
    __syncthreads();
#pragma unroll
    for (int i = 0; i < 4; ++i) {
        int n = n0 + ty + i * 8;
        Wt[(size_t)n * HID + k0 + tx] = __float2bfloat16(t[tx][ty + i * 8]);
    }
}

// ---------------------------------------------------------------- transpose+cast
__global__ void k_tr_cast(const float* __restrict__ src, bf16* __restrict__ dst, int R, int Ccol) {
    __shared__ float t[32][33];
    const int c0 = blockIdx.x * 32, r0 = blockIdx.y * 32;
    const int tx = threadIdx.x, ty = threadIdx.y;
#pragma unroll
    for (int i = 0; i < 4; ++i)
        t[ty + i * 8][tx] = src[(size_t)(r0 + ty + i * 8) * Ccol + c0 + tx];
    __syncthreads();
#pragma unroll
    for (int i = 0; i < 4; ++i)
        dst[(size_t)(c0 + ty + i * 8) * R + r0 + tx] = __float2bfloat16(t[tx][ty + i * 8]);
}

// ---------------------------------------------------------------- alpha/beta
__global__ __launch_bounds__(256) void k_ab(const float* __restrict__ hs, const float* __restrict__ Wa,
                                            const float* __restrict__ Wb,
                                            float* __restrict__ alpha, float* __restrict__ beta) {
    const int tok = blockIdx.x;
    const int tid = threadIdx.x;
    float part[12];
#pragma unroll
    for (int j = 0; j < 12; ++j) part[j] = 0.f;
    const float* hrow = hs + (size_t)tok * HID;
    for (int i = 0; i < 8; ++i) {
        int k = i * 256 + tid;
        float x = hrow[k];
        const float* wa = Wa + k * NH;
        const float* wb = Wb + k * NH;
#pragma unroll
        for (int j = 0; j < NH; ++j) {
            part[j]     = fmaf(x, wa[j], part[j]);
            part[6 + j] = fmaf(x, wb[j], part[6 + j]);
        }
    }
    __shared__ float red[12][4];
    const int lane = tid & 63, wv = tid >> 6;
#pragma unroll
    for (int j = 0; j < 12; ++j) {
        float s = part[j];
        for (int off = 32; off; off >>= 1) s += __shfl_down(s, off);
        if (lane == 0) red[j][wv] = s;
    }
    __syncthreads();
    if (tid < 12) {
        float s = red[tid][0] + red[tid][1] + red[tid][2] + red[tid][3];
        float v = 1.f / (1.f + expf(-s));
        if (tid < 6) alpha[(size_t)tok * NH + tid] = v;
        else         beta [(size_t)tok * NH + tid - 6] = v;
    }
}

// ---------------------------------------------------------------- conv + phase + rotate + local chunk scan
__global__ __launch_bounds__(256) void k_scan1(const bf16* __restrict__ X,
                                               const float* __restrict__ alpha,
                                               const float* __restrict__ beta,
                                               const float* __restrict__ cq,
                                               const float* __restrict__ ck,
                                               const float* __restrict__ cv,
                                               float* __restrict__ U, float* __restrict__ pp) {
    const int bx = blockIdx.x;
    const int c  = bx % NC;
    const int h  = (bx / NC) % NH;
    const int b  = bx / (NC * NH);
    const int p  = threadIdx.x;
    const int t0 = c * CHUNK;
    const int ch2 = h * HD + 2 * p;
    const float wq0 = cq[ch2 * 4 + 0], wq1 = cq[ch2 * 4 + 1], wq2 = cq[ch2 * 4 + 2], wq3 = cq[ch2 * 4 + 3];
    const float wk0 = ck[ch2 * 4 + 0], wk1 = ck[ch2 * 4 + 1], wk2 = ck[ch2 * 4 + 2], wk3 = ck[ch2 * 4 + 3];
    const float wa0 = cv[ch2 * 4 + 0], wa1 = cv[ch2 * 4 + 1], wa2 = cv[ch2 * 4 + 2], wa3 = cv[ch2 * 4 + 3];
    const float wb0 = cv[(ch2 + 1) * 4 + 0], wb1 = cv[(ch2 + 1) * 4 + 1],
                wb2 = cv[(ch2 + 1) * 4 + 2], wb3 = cv[(ch2 + 1) * 4 + 3];
    const float invf = exp2f(-13.287712379549449f * ((float)p * (1.0f / 256.0f)));
    const int qcol = h * NPAIR + p;
    const int kcol = 1536 + h * NPAIR + p;
    const int vcol = 3072 + ch2;

    float xq[3], xk[3], xv0[3], xv1[3];
#pragma unroll
    for (int i = 0; i < 3; ++i) {
        int t = t0 - 3 + i;
        if (t >= 0) {
            size_t tok = (size_t)b * 2048 + t;
            const bf16* xr = X + tok * N1;
            xq[i] = __bfloat162float(xr[qcol]);
            xk[i] = __bfloat162float(xr[kcol]);
            __hip_bfloat162 vv = *(const __hip_bfloat162*)&xr[vcol];
            xv0[i] = __bfloat162float(vv.x);
            xv1[i] = __bfloat162float(vv.y);
        } else { xq[i] = xk[i] = xv0[i] = xv1[i] = 0.f; }
    }

    float u0 = 0.f, u1 = 0.f, ap = 1.f;
    for (int t = t0; t < t0 + CHUNK; ++t) {
        const size_t tok = (size_t)b * 2048 + t;
        const bf16* xr = X + tok * N1;
        float nq = __bfloat162float(xr[qcol]);
        float nk = __bfloat162float(xr[kcol]);
        __hip_bfloat162 vv = *(const __hip_bfloat162*)&xr[vcol];
        float nv0 = __bfloat162float(vv.x);
        float nv1 = __bfloat162float(vv.y);
        float yq  = wq3 * nq  + wq2 * xq[2]  + wq1 * xq[1]  + wq0 * xq[0];
        float yk  = wk3 * nk  + wk2 * xk[2]  + wk1 * xk[1]  + wk0 * xk[0];
        float yv0 = wa3 * nv0 + wa2 * xv0[2] + wa1 * xv0[1] + wa0 * xv0[0];
        float yv1 = wb3 * nv1 + wb2 * xv1[2] + wb1 * xv1[1] + wb0 * xv1[0];
        xq[0] = xq[1]; xq[1] = xq[2]; xq[2] = nq;
        xk[0] = xk[1]; xk[1] = xk[2]; xk[2] = nk;
        xv0[0] = xv0[1]; xv0[1] = xv0[2]; xv0[2] = nv0;
        xv1[0] = xv1[1]; xv1[1] = xv1[2]; xv1[2] = nv1;
        float theta = yq * invf, psi = yk * invf;
        float d = psi - theta, sn, cs;
        __sincosf(d, &sn, &cs);
        float w0 = yv0 * cs - yv1 * sn;
        float w1 = yv1 * cs + yv0 * sn;
        float a  = alpha[tok * NH + h];
        float bb = beta [tok * NH + h];
        u0 = fmaf(a, u0, bb * w0);
        u1 = fmaf(a, u1, bb * w1);
        ap *= a;
        *(float2*)&U[tok * (size_t)VD + h * HD + 2 * p] = float2{u0, u1};
        if (p == 0) pp[tok * NH + h] = ap;
    }
}

// ---------------------------------------------------------------- cross-chunk carry
__global__ void k_carry(const float* __restrict__ U, const float* __restrict__ pp,
                        float* __restrict__ carry) {
    const int bh = blockIdx.x;
    const int b = bh / NH, h = bh % NH;
    const int tid = threadIdx.x;
    for (int half = 0; half < 2; ++half) {
        const int d = tid + half * 256;
        float s = 0.f;
        for (int c = 0; c < NC; ++c) {
            carry[((size_t)bh * NC + c) * HD + d] = s;
            int tend = c * CHUNK + CHUNK - 1;
            size_t tok = (size_t)b * 2048 + tend;
            s = U[tok * (size_t)VD + h * HD + d] + pp[tok * NH + h] * s;
        }
    }
}

// ---------------------------------------------------------------- carry fix + RMS + SiLU gate -> bf16 O
__global__ __launch_bounds__(256) void k_pass3(const float* __restrict__ U, const float* __restrict__ pp,
                                               const float* __restrict__ carry, const bf16* __restrict__ X,
                                               const float* __restrict__ rms_w, bf16* __restrict__ O) {
    const int bx = blockIdx.x;
    const int h = bx % NH;
    const size_t tok = bx / NH;
    const int b = (int)(tok >> 11);
    const int t = (int)(tok & 2047);
    const int c = t / CHUNK;
    const int tid = threadIdx.x;
    const int d = tid * 2;
    float2 uu = *(const float2*)&U[tok * (size_t)VD + h * HD + d];
    float  P  = pp[tok * NH + h];
    float2 cy = *(const float2*)&carry[((size_t)(b * NH + h) * NC + c) * HD + d];
    float u0 = fmaf(P, cy.x, uu.x);
    float u1 = fmaf(P, cy.y, uu.y);
    float s = u0 * u0 + u1 * u1;
    for (int off = 32; off; off >>= 1) s += __shfl_down(s, off);
    __shared__ float r4[4];
    const int lane = tid & 63, wv = tid >> 6;
    if (lane == 0) r4[wv] = s;
    __syncthreads();
    float tot = r4[0] + r4[1] + r4[2] + r4[3];
    float rms = rsqrtf(tot * (1.f / 512.f) + 1e-5f);
    __hip_bfloat162 gg = *(const __hip_bfloat162*)&X[tok * N1 + 6144 + h * HD + d];
    float g0 = __bfloat162float(gg.x), g1 = __bfloat162float(gg.y);
    float si0 = g0 / (1.f + expf(-g0));
    float si1 = g1 / (1.f + expf(-g1));
    float o0 = u0 * rms * rms_w[d]     * si0;
    float o1 = u1 * rms * rms_w[d + 1] * si1;
    __hip_bfloat162 ob;
    ob.x = __float2bfloat16(o0);
    ob.y = __float2bfloat16(o1);
    *(__hip_bfloat162*)&O[tok * (size_t)VD + h * HD + d] = ob;
}

// ----------------------------------------------------------------
extern "C" void kernel_launch(void* const* d_in, const int* in_sizes, int n_in,
                              void* d_out, int out_size, void* d_ws, size_t ws_size,
                              hipStream_t stream) {
    const float* hs   = (const float*)d_in[0];
    const float* Wq   = (const float*)d_in[1];
    const float* Wk   = (const float*)d_in[2];
    const float* Wv   = (const float*)d_in[3];
    const float* Wa   = (const float*)d_in[4];
    const float* Wb   = (const float*)d_in[5];
    const float* Wg   = (const float*)d_in[6];
    const float* Wo   = (const float*)d_in[7];
    const float* cq   = (const float*)d_in[8];
    const float* ck   = (const float*)d_in[9];
    const float* cv   = (const float*)d_in[10];
    const float* rmsw = (const float*)d_in[11];

    char* ws = (char*)d_ws;
    size_t off = 0;
    auto alloc = [&](size_t bytes) -> void* {
        void* p = ws + off;
        off = (off + bytes + 255) & ~(size_t)255;
        return p;
    };
    bf16*  hsb   = (bf16*) alloc((size_t)TOKENS * HID * 2);
    bf16*  Wt    = (bf16*) alloc((size_t)N1 * HID * 2);
    bf16*  Wot   = (bf16*) alloc((size_t)HID * VD * 2);
    bf16*  X     = (bf16*) alloc((size_t)TOKENS * N1 * 2);
    float* U     = (float*)alloc((size_t)TOKENS * VD * 4);
    float* alp   = (float*)alloc((size_t)TOKENS * NH * 4);
    float* bet   = (float*)alloc((size_t)TOKENS * NH * 4);
    float* pp    = (float*)alloc((size_t)TOKENS * NH * 4);
    float* carry = (float*)alloc((size_t)2 * NH * NC * HD * 4);
    bf16*  O     = (bf16*)Wt;   // alias: Wt dead after GEMM-1

    hipFuncSetAttribute((const void*)k_gemm8,
                        hipFuncAttributeMaxDynamicSharedMemorySize, G8_SMEM);
    hipFuncSetAttribute((const void*)k_gemm_p,
                        hipFuncAttributeMaxDynamicSharedMemorySize, SMEM_BYTES);

    k_cast_bf16<<<TOKENS * HID / 1024, 256, 0, stream>>>(hs, hsb, TOKENS * HID);
    k_prep_w<<<dim3(N1 / 32, HID / 32), dim3(32, 8), 0, stream>>>(Wq, Wk, Wv, Wg, Wt);
    k_tr_cast<<<dim3(HID / 32, VD / 32), dim3(32, 8), 0, stream>>>(Wo, Wot, VD, HID);
    k_ab<<<TOKENS, 256, 0, stream>>>(hs, Wa, Wb, alp, bet);
    // X = hsb @ Wt^T   (M=4096, N=9216, K=2048) -> 16*36 = 576 blocks (8-phase 256^2)
    k_gemm8<<<dim3((TOKENS / 256) * (N1 / 256)), 512, G8_SMEM, stream>>>(hsb, Wt, X, TOKENS, N1, HID, 1);
    k_scan1<<<2 * NH * NC, 256, 0, stream>>>(X, alp, bet, cq, ck, cv, U, pp);
    k_carry<<<2 * NH, 256, 0, stream>>>(U, pp, carry);
    k_pass3<<<TOKENS * NH, 256, 0, stream>>>(U, pp, carry, X, rmsw, O);
    // out = O @ Wot^T  (M=4096, N=2048, K=3072) -> 256 blocks (256x128 pipelined)
    k_gemm_p<<<dim3((TOKENS / BM) * (HID / BN)), 512, SMEM_BYTES, stream>>>(O, Wot, d_out, TOKENS, HID, VD, 0);
}

// Round 8
// 360.341 us; speedup vs baseline: 12.8397x; 1.1074x over previous
//
#include <hip/hip_runtime.h>
#include <hip/hip_bf16.h>
#include <stdint.h>

using bf16 = __hip_bfloat16;
using mfrag = __attribute__((ext_vector_type(8))) __bf16;   // 8 bf16 = 4 VGPRs
using f32x4 = __attribute__((ext_vector_type(4))) float;

#define TOKENS 4096
#define HID    2048
#define VD     3072
#define NH     6
#define HD     512
#define NPAIR  256
#define N1     9216     /* q_even(1536) | k_even(1536) | v(3072) | g(3072) */
#define NC     64
#define CHUNK  32

__device__ __forceinline__ void gld_lds16(const bf16* g, bf16* l) {
    __builtin_amdgcn_global_load_lds((const __attribute__((address_space(1))) void*)g,
                                     (__attribute__((address_space(3))) void*)l, 16, 0, 0);
}

// ================================================================ single-barrier 256xBN GEMM
// A: (M,K) bf16 row-major; Bt: (N,K) bf16 row-major (B^T). C: (M,N) bf16 or f32.
// BM=256, BK=64, 512 threads = 8 waves. BN=256: 2Mx4N waves (128x64 each);
// BN=128: 4Mx2N waves (64x64 each). Double-buffered LDS; stage-all-first;
// ONE vmcnt(0)+barrier per K-step; frag reads are plain loads so the compiler
// interleaves ds_read with MFMA via counted lgkmcnt.
template<int BN_T>
__global__ __launch_bounds__(512, 2) void k_gemm2(const bf16* __restrict__ A,
                                                  const bf16* __restrict__ Bt,
                                                  void* __restrict__ Cv,
                                                  int M, int N, int K, int obf) {
    constexpr int WN   = (BN_T == 256) ? 4 : 2;   // col-band waves (64 cols each)
    constexpr int WM   = 8 / WN;                  // row-band waves
    constexpr int MF   = (256 / WM) / 16;         // A frags per wave (8 or 4)
    constexpr int NHT  = 2 + BN_T / 128;          // half-tiles per buffer (4 or 3)
    constexpr int HT   = 16384;                   // 128x64x2B half-tile
    constexpr int SLOT = NHT * HT;

    extern __shared__ char smem[];
    const int tid  = threadIdx.x;
    const int wave = tid >> 6;
    const int lane = tid & 63;
    const int lrow = lane & 15;
    const int lk   = lane >> 4;
    const int wm   = wave / WN;
    const int wn   = wave % WN;

    // XCD-aware bijective swizzle (grids here are multiples of 8)
    const int nbn = N / BN_T;
    const int cpx = gridDim.x >> 3;
    const int bid = blockIdx.x;
    const int swz = (bid & 7) * cpx + (bid >> 3);
    const int bm  = (swz / nbn) << 8;
    const int bn  = (swz % nbn) * BN_T;

    const int NT = K >> 6;

    // stage one 128x64 half-tile: dest linear, source chunk pre-swizzled (rule 21)
    auto stage_ht = [&](const bf16* src, int row0, char* htb, int koff) {
#pragma unroll
        for (int i = 0; i < 2; ++i) {
            const int L = i * 512 + tid;
            const int r = L >> 3;
            const int c = (L & 7) ^ (r & 7);
            gld_lds16(src + (size_t)(row0 + r) * K + koff + c * 8,
                      (bf16*)(htb + (size_t)L * 16));
        }
    };
    auto STAGE = [&](int t, char* sb) {
        const int ko = t << 6;
        stage_ht(A, bm,       sb,          ko);
        stage_ht(A, bm + 128, sb + HT,     ko);
        stage_ht(Bt, bn,      sb + 2 * HT, ko);
        if (BN_T == 256) stage_ht(Bt, bn + 128, sb + 3 * HT, ko);
    };

    // swizzled fragment reads (plain loads -> compiler-scheduled waits)
    auto rdA = [&](const char* rb, int mf, int kk) -> mfrag {
        const int r  = wm * (MF * 16) + mf * 16 + lrow;
        const int ht = r >> 7, lr = r & 127;
        const int cc = (kk * 4 + lk) ^ (lr & 7);
        return *(const mfrag*)(rb + (size_t)ht * HT + (size_t)lr * 128 + cc * 16);
    };
    auto rdB = [&](const char* rb, int nf, int kk) -> mfrag {
        const int r  = wn * 64 + nf * 16 + lrow;
        const int ht = r >> 7, lr = r & 127;
        const int cc = (kk * 4 + lk) ^ (lr & 7);
        return *(const mfrag*)(rb + (size_t)(2 + ht) * HT + (size_t)lr * 128 + cc * 16);
    };

    f32x4 acc[MF][4];
#pragma unroll
    for (int m = 0; m < MF; ++m)
#pragma unroll
        for (int n = 0; n < 4; ++n) acc[m][n] = f32x4{0.f, 0.f, 0.f, 0.f};

    // prologue
    STAGE(0, smem);
    asm volatile("s_waitcnt vmcnt(0)" ::: "memory");
    __builtin_amdgcn_sched_barrier(0);
    __builtin_amdgcn_s_barrier();

    for (int kt = 0; kt < NT; ++kt) {
        char* rb = smem + (size_t)(kt & 1) * SLOT;
        char* wb = smem + (size_t)((kt + 1) & 1) * SLOT;
        if (kt + 1 < NT) STAGE(kt + 1, wb);   // issue first: ~full K-step of flight

        mfrag bfr[4][2];
#pragma unroll
        for (int nf = 0; nf < 4; ++nf)
#pragma unroll
            for (int kk = 0; kk < 2; ++kk) bfr[nf][kk] = rdB(rb, nf, kk);

#pragma unroll
        for (int h2 = 0; h2 < 2; ++h2) {      // two A-halves to cap register liveness
            mfrag af[MF / 2][2];
#pragma unroll
            for (int mf = 0; mf < MF / 2; ++mf)
#pragma unroll
                for (int kk = 0; kk < 2; ++kk) af[mf][kk] = rdA(rb, h2 * (MF / 2) + mf, kk);
            __builtin_amdgcn_s_setprio(1);
#pragma unroll
            for (int mf = 0; mf < MF / 2; ++mf)
#pragma unroll
                for (int nf = 0; nf < 4; ++nf) {
                    const int mi = h2 * (MF / 2) + mf;
                    acc[mi][nf] = __builtin_amdgcn_mfma_f32_16x16x32_bf16(af[mf][0], bfr[nf][0], acc[mi][nf], 0, 0, 0);
                    acc[mi][nf] = __builtin_amdgcn_mfma_f32_16x16x32_bf16(af[mf][1], bfr[nf][1], acc[mi][nf], 0, 0, 0);
                }
            __builtin_amdgcn_s_setprio(0);
        }

        if (kt + 1 < NT) {
            asm volatile("s_waitcnt vmcnt(0)" ::: "memory");  // next buffer landed (long flight)
            __builtin_amdgcn_sched_barrier(0);
            __builtin_amdgcn_s_barrier();                     // swap point (reads all consumed)
            __builtin_amdgcn_sched_barrier(0);
        }
    }

    // epilogue
#pragma unroll
    for (int m = 0; m < MF; ++m)
#pragma unroll
        for (int j = 0; j < 4; ++j) {
            const int r = bm + wm * (MF * 16) + m * 16 + lk * 4 + j;
#pragma unroll
            for (int n = 0; n < 4; ++n) {
                const int c = bn + wn * 64 + n * 16 + lrow;
                if (obf) ((bf16*)Cv)[(size_t)r * N + c] = __float2bfloat16(acc[m][n][j]);
                else     ((float*)Cv)[(size_t)r * N + c] = acc[m][n][j];
            }
        }
}

// ---------------------------------------------------------------- fused weight build
__global__ void k_prep_w(const float* __restrict__ Wq, const float* __restrict__ Wk,
                         const float* __restrict__ Wv, const float* __restrict__ Wg,
                         bf16* __restrict__ Wt) {
    __shared__ float t[32][33];
    const int n0 = blockIdx.x * 32;
    const int k0 = blockIdx.y * 32;
    const int tx = threadIdx.x, ty = threadIdx.y;
    const float* src; int cb, cs;
    if (n0 < 1536)      { int m = n0;        src = Wq; cb = (m >> 8) * 512 + (m & 255) * 2; cs = 2; }
    else if (n0 < 3072) { int m = n0 - 1536; src = Wk; cb = (m >> 8) * 512 + (m & 255) * 2; cs = 2; }
    else if (n0 < 6144) { int m = n0 - 3072; src = Wv; cb = m; cs = 1; }
    else                { int m = n0 - 6144; src = Wg; cb = m; cs = 1; }
#pragma unroll
    for (int i = 0; i < 4; ++i) {
        int k = k0 + ty + i * 8;
        t[ty + i * 8][tx] = src[(size_t)k * VD + cb + cs * tx];
    }
    __syncthreads();
#pragma unroll
    for (int i = 0; i < 4; ++i) {
        int n = n0 + ty + i * 8;
        Wt[(size_t)n * HID + k0 + tx] = __float2bfloat16(t[tx][ty + i * 8]);
    }
}

// ---------------------------------------------------------------- transpose+cast
__global__ void k_tr_cast(const float* __restrict__ src, bf16* __restrict__ dst, int R, int Ccol) {
    __shared__ float t[32][33];
    const int c0 = blockIdx.x * 32, r0 = blockIdx.y * 32;
    const int tx = threadIdx.x, ty = threadIdx.y;
#pragma unroll
    for (int i = 0; i < 4; ++i)
        t[ty + i * 8][tx] = src[(size_t)(r0 + ty + i * 8) * Ccol + c0 + tx];
    __syncthreads();
#pragma unroll
    for (int i = 0; i < 4; ++i)
        dst[(size_t)(c0 + ty + i * 8) * R + r0 + tx] = __float2bfloat16(t[tx][ty + i * 8]);
}

// ---------------------------------------------------------------- alpha/beta + hs->bf16 cast (fused)
__global__ __launch_bounds__(256) void k_ab(const float* __restrict__ hs, const float* __restrict__ Wa,
                                            const float* __restrict__ Wb,
                                            float* __restrict__ alpha, float* __restrict__ beta,
                                            bf16* __restrict__ hsb) {
    const int tok = blockIdx.x;
    const int tid = threadIdx.x;
    float part[12];
#pragma unroll
    for (int j = 0; j < 12; ++j) part[j] = 0.f;
    const float* hrow = hs + (size_t)tok * HID;
    bf16* hbrow = hsb + (size_t)tok * HID;
    for (int i = 0; i < 8; ++i) {
        int k = i * 256 + tid;
        float x = hrow[k];
        hbrow[k] = __float2bfloat16(x);
        const float* wa = Wa + k * NH;
        const float* wb = Wb + k * NH;
#pragma unroll
        for (int j = 0; j < NH; ++j) {
            part[j]     = fmaf(x, wa[j], part[j]);
            part[6 + j] = fmaf(x, wb[j], part[6 + j]);
        }
    }
    __shared__ float red[12][4];
    const int lane = tid & 63, wv = tid >> 6;
#pragma unroll
    for (int j = 0; j < 12; ++j) {
        float s = part[j];
        for (int off = 32; off; off >>= 1) s += __shfl_down(s, off);
        if (lane == 0) red[j][wv] = s;
    }
    __syncthreads();
    if (tid < 12) {
        float s = red[tid][0] + red[tid][1] + red[tid][2] + red[tid][3];
        float v = 1.f / (1.f + expf(-s));
        if (tid < 6) alpha[(size_t)tok * NH + tid] = v;
        else         beta [(size_t)tok * NH + tid - 6] = v;
    }
}

// ---------------------------------------------------------------- conv + phase + rotate + local chunk scan
__global__ __launch_bounds__(256) void k_scan1(const bf16* __restrict__ X,
                                               const float* __restrict__ alpha,
                                               const float* __restrict__ beta,
                                               const float* __restrict__ cq,
                                               const float* __restrict__ ck,
                                               const float* __restrict__ cv,
                                               float* __restrict__ U, float* __restrict__ pp) {
    const int bx = blockIdx.x;
    const int c  = bx % NC;
    const int h  = (bx / NC) % NH;
    const int b  = bx / (NC * NH);
    const int p  = threadIdx.x;
    const int t0 = c * CHUNK;
    const int ch2 = h * HD + 2 * p;
    const float wq0 = cq[ch2 * 4 + 0], wq1 = cq[ch2 * 4 + 1], wq2 = cq[ch2 * 4 + 2], wq3 = cq[ch2 * 4 + 3];
    const float wk0 = ck[ch2 * 4 + 0], wk1 = ck[ch2 * 4 + 1], wk2 = ck[ch2 * 4 + 2], wk3 = ck[ch2 * 4 + 3];
    const float wa0 = cv[ch2 * 4 + 0], wa1 = cv[ch2 * 4 + 1], wa2 = cv[ch2 * 4 + 2], wa3 = cv[ch2 * 4 + 3];
    const float wb0 = cv[(ch2 + 1) * 4 + 0], wb1 = cv[(ch2 + 1) * 4 + 1],
                wb2 = cv[(ch2 + 1) * 4 + 2], wb3 = cv[(ch2 + 1) * 4 + 3];
    const float invf = exp2f(-13.287712379549449f * ((float)p * (1.0f / 256.0f)));
    const int qcol = h * NPAIR + p;
    const int kcol = 1536 + h * NPAIR + p;
    const int vcol = 3072 + ch2;

    float xq[3], xk[3], xv0[3], xv1[3];
#pragma unroll
    for (int i = 0; i < 3; ++i) {
        int t = t0 - 3 + i;
        if (t >= 0) {
            size_t tok = (size_t)b * 2048 + t;
            const bf16* xr = X + tok * N1;
            xq[i] = __bfloat162float(xr[qcol]);
            xk[i] = __bfloat162float(xr[kcol]);
            __hip_bfloat162 vv = *(const __hip_bfloat162*)&xr[vcol];
            xv0[i] = __bfloat162float(vv.x);
            xv1[i] = __bfloat162float(vv.y);
        } else { xq[i] = xk[i] = xv0[i] = xv1[i] = 0.f; }
    }

    float u0 = 0.f, u1 = 0.f, ap = 1.f;
    for (int t = t0; t < t0 + CHUNK; ++t) {
        const size_t tok = (size_t)b * 2048 + t;
        const bf16* xr = X + tok * N1;
        float nq = __bfloat162float(xr[qcol]);
        float nk = __bfloat162float(xr[kcol]);
        __hip_bfloat162 vv = *(const __hip_bfloat162*)&xr[vcol];
        float nv0 = __bfloat162float(vv.x);
        float nv1 = __bfloat162float(vv.y);
        float yq  = wq3 * nq  + wq2 * xq[2]  + wq1 * xq[1]  + wq0 * xq[0];
        float yk  = wk3 * nk  + wk2 * xk[2]  + wk1 * xk[1]  + wk0 * xk[0];
        float yv0 = wa3 * nv0 + wa2 * xv0[2] + wa1 * xv0[1] + wa0 * xv0[0];
        float yv1 = wb3 * nv1 + wb2 * xv1[2] + wb1 * xv1[1] + wb0 * xv1[0];
        xq[0] = xq[1]; xq[1] = xq[2]; xq[2] = nq;
        xk[0] = xk[1]; xk[1] = xk[2]; xk[2] = nk;
        xv0[0] = xv0[1]; xv0[1] = xv0[2]; xv0[2] = nv0;
        xv1[0] = xv1[1]; xv1[1] = xv1[2]; xv1[2] = nv1;
        float theta = yq * invf, psi = yk * invf;
        float d = psi - theta, sn, cs;
        __sincosf(d, &sn, &cs);
        float w0 = yv0 * cs - yv1 * sn;
        float w1 = yv1 * cs + yv0 * sn;
        float a  = alpha[tok * NH + h];
        float bb = beta [tok * NH + h];
        u0 = fmaf(a, u0, bb * w0);
        u1 = fmaf(a, u1, bb * w1);
        ap *= a;
        *(float2*)&U[tok * (size_t)VD + h * HD + 2 * p] = float2{u0, u1};
        if (p == 0) pp[tok * NH + h] = ap;
    }
}

// ---------------------------------------------------------------- cross-chunk carry (prefetched recurrence)
__global__ __launch_bounds__(512) void k_carry(const float* __restrict__ U, const float* __restrict__ pp,
                                               float* __restrict__ carry) {
    const int bh = blockIdx.x;              // 0..11 = b*NH+h
    const int b = bh / NH, h = bh % NH;
    const int d = threadIdx.x;              // 0..511
    float ue[NC], pv[NC];
#pragma unroll
    for (int c = 0; c < NC; ++c) {          // independent loads: all in flight
        size_t tok = (size_t)b * 2048 + c * CHUNK + CHUNK - 1;
        ue[c] = U[tok * (size_t)VD + h * HD + d];
        pv[c] = pp[tok * NH + h];
    }
    float s = 0.f;
#pragma unroll
    for (int c = 0; c < NC; ++c) {
        carry[((size_t)bh * NC + c) * HD + d] = s;
        s = ue[c] + pv[c] * s;
    }
}

// ---------------------------------------------------------------- carry fix + RMS + SiLU gate -> bf16 O
__global__ __launch_bounds__(256) void k_pass3(const float* __restrict__ U, const float* __restrict__ pp,
                                               const float* __restrict__ carry, const bf16* __restrict__ X,
                                               const float* __restrict__ rms_w, bf16* __restrict__ O) {
    const int bx = blockIdx.x;
    const int h = bx % NH;
    const size_t tok = bx / NH;
    const int b = (int)(tok >> 11);
    const int t = (int)(tok & 2047);
    const int c = t / CHUNK;
    const int tid = threadIdx.x;
    const int d = tid * 2;
    float2 uu = *(const float2*)&U[tok * (size_t)VD + h * HD + d];
    float  P  = pp[tok * NH + h];
    float2 cy = *(const float2*)&carry[((size_t)(b * NH + h) * NC + c) * HD + d];
    float u0 = fmaf(P, cy.x, uu.x);
    float u1 = fmaf(P, cy.y, uu.y);
    float s = u0 * u0 + u1 * u1;
    for (int off = 32; off; off >>= 1) s += __shfl_down(s, off);
    __shared__ float r4[4];
    const int lane = tid & 63, wv = tid >> 6;
    if (lane == 0) r4[wv] = s;
    __syncthreads();
    float tot = r4[0] + r4[1] + r4[2] + r4[3];
    float rms = rsqrtf(tot * (1.f / 512.f) + 1e-5f);
    __hip_bfloat162 gg = *(const __hip_bfloat162*)&X[tok * N1 + 6144 + h * HD + d];
    float g0 = __bfloat162float(gg.x), g1 = __bfloat162float(gg.y);
    float si0 = g0 / (1.f + expf(-g0));
    float si1 = g1 / (1.f + expf(-g1));
    float o0 = u0 * rms * rms_w[d]     * si0;
    float o1 = u1 * rms * rms_w[d + 1] * si1;
    __hip_bfloat162 ob;
    ob.x = __float2bfloat16(o0);
    ob.y = __float2bfloat16(o1);
    *(__hip_bfloat162*)&O[tok * (size_t)VD + h * HD + d] = ob;
}

// ----------------------------------------------------------------
extern "C" void kernel_launch(void* const* d_in, const int* in_sizes, int n_in,
                              void* d_out, int out_size, void* d_ws, size_t ws_size,
                              hipStream_t stream) {
    const float* hs   = (const float*)d_in[0];
    const float* Wq   = (const float*)d_in[1];
    const float* Wk   = (const float*)d_in[2];
    const float* Wv   = (const float*)d_in[3];
    const float* Wa   = (const float*)d_in[4];
    const float* Wb   = (const float*)d_in[5];
    const float* Wg   = (const float*)d_in[6];
    const float* Wo   = (const float*)d_in[7];
    const float* cq   = (const float*)d_in[8];
    const float* ck   = (const float*)d_in[9];
    const float* cv   = (const float*)d_in[10];
    const float* rmsw = (const float*)d_in[11];

    char* ws = (char*)d_ws;
    size_t off = 0;
    auto alloc = [&](size_t bytes) -> void* {
        void* p = ws + off;
        off = (off + bytes + 255) & ~(size_t)255;
        return p;
    };
    bf16*  hsb   = (bf16*) alloc((size_t)TOKENS * HID * 2);
    bf16*  Wt    = (bf16*) alloc((size_t)N1 * HID * 2);
    bf16*  Wot   = (bf16*) alloc((size_t)HID * VD * 2);
    bf16*  X     = (bf16*) alloc((size_t)TOKENS * N1 * 2);
    float* U     = (float*)alloc((size_t)TOKENS * VD * 4);
    float* alp   = (float*)alloc((size_t)TOKENS * NH * 4);
    float* bet   = (float*)alloc((size_t)TOKENS * NH * 4);
    float* pp    = (float*)alloc((size_t)TOKENS * NH * 4);
    float* carry = (float*)alloc((size_t)2 * NH * NC * HD * 4);
    bf16*  O     = (bf16*)Wt;   // alias: Wt dead after GEMM-1

    hipFuncSetAttribute((const void*)k_gemm2<256>,
                        hipFuncAttributeMaxDynamicSharedMemorySize, 2 * 4 * 16384);
    hipFuncSetAttribute((const void*)k_gemm2<128>,
                        hipFuncAttributeMaxDynamicSharedMemorySize, 2 * 3 * 16384);

    k_prep_w<<<dim3(N1 / 32, HID / 32), dim3(32, 8), 0, stream>>>(Wq, Wk, Wv, Wg, Wt);
    k_tr_cast<<<dim3(HID / 32, VD / 32), dim3(32, 8), 0, stream>>>(Wo, Wot, VD, HID);
    k_ab<<<TOKENS, 256, 0, stream>>>(hs, Wa, Wb, alp, bet, hsb);
    // X = hsb @ Wt^T   (M=4096, N=9216, K=2048) -> 16*36 = 576 blocks
    k_gemm2<256><<<dim3((TOKENS / 256) * (N1 / 256)), 512, 2 * 4 * 16384, stream>>>(hsb, Wt, X, TOKENS, N1, HID, 1);
    k_scan1<<<2 * NH * NC, 256, 0, stream>>>(X, alp, bet, cq, ck, cv, U, pp);
    k_carry<<<2 * NH, 512, 0, stream>>>(U, pp, carry);
    k_pass3<<<TOKENS * NH, 256, 0, stream>>>(U, pp, carry, X, rmsw, O);
    // out = O @ Wot^T  (M=4096, N=2048, K=3072) -> 16*16 = 256 blocks
    k_gemm2<128><<<dim3((TOKENS / 256) * (HID / 128)), 512, 2 * 3 * 16384, stream>>>(O, Wot, d_out, TOKENS, HID, VD, 0);
}

// Round 9
// 353.263 us; speedup vs baseline: 13.0970x; 1.0200x over previous
//
#include <hip/hip_runtime.h>
#include <hip/hip_bf16.h>
#include <stdint.h>

using bf16 = __hip_bfloat16;
using mfrag = __attribute__((ext_vector_type(8))) __bf16;   // 8 bf16 = 4 VGPRs
using f32x4 = __attribute__((ext_vector_type(4))) float;

#define TOKENS 4096
#define HID    2048
#define VD     3072
#define NH     6
#define HD     512
#define NPAIR  256
#define N1     9216     /* q_even(1536) | k_even(1536) | v(3072) | g(3072) */
#define NC     64
#define CHUNK  32

__device__ __forceinline__ void gld_lds16(const bf16* g, bf16* l) {
    __builtin_amdgcn_global_load_lds((const __attribute__((address_space(1))) void*)g,
                                     (__attribute__((address_space(3))) void*)l, 16, 0, 0);
}

// ================================================================ single-barrier 256xBN GEMM
// A: (M,K) bf16 row-major; Bt: (N,K) bf16 row-major (B^T). C: (M,N) bf16 or f32.
// BM=256, BK=64, 512 threads = 8 waves. Supertile-per-XCD block mapping:
// XCD x owns a 4-row x (nbn/2)-col region; its blocks come in 4x8 supertiles so
// the 32 co-resident blocks per XCD share 4 A-panels + 8 B-panels (L2 reuse).
template<int BN_T>
__global__ __launch_bounds__(512, 2) void k_gemm2(const bf16* __restrict__ A,
                                                  const bf16* __restrict__ Bt,
                                                  void* __restrict__ Cv,
                                                  int M, int N, int K, int obf) {
    constexpr int WN   = (BN_T == 256) ? 4 : 2;   // col-band waves (64 cols each)
    constexpr int WM   = 8 / WN;                  // row-band waves
    constexpr int MF   = (256 / WM) / 16;         // A frags per wave (8 or 4)
    constexpr int NHT  = 2 + BN_T / 128;          // half-tiles per buffer (4 or 3)
    constexpr int HT   = 16384;                   // 128x64x2B half-tile
    constexpr int SLOT = NHT * HT;

    extern __shared__ char smem[];
    const int tid  = threadIdx.x;
    const int wave = tid >> 6;
    const int lane = tid & 63;
    const int lrow = lane & 15;
    const int lk   = lane >> 4;
    const int wm   = wave / WN;
    const int wn   = wave % WN;

    // supertile-per-XCD mapping (bijective for grid = 8 * 4 * (nbn/2))
    const int nbn = N / BN_T;
    const int bid = blockIdx.x;
    const int xcd = bid & 7;              // HW dispatch round-robins XCDs
    const int k   = bid >> 3;             // slot within XCD
    const int rn  = nbn >> 1;             // region cols per XCD
    const int j   = k & 31;               // position in 4x8 supertile
    const int bm  = ((((xcd >> 1) << 2) + (j & 3)) << 8);
    const int bn  = ((xcd & 1) * rn + (k >> 5) * 8 + (j >> 2)) * BN_T;

    const int NT = K >> 6;

    // stage one 128x64 half-tile: dest linear, source chunk pre-swizzled (rule 21)
    auto stage_ht = [&](const bf16* src, int row0, char* htb, int koff) {
#pragma unroll
        for (int i = 0; i < 2; ++i) {
            const int L = i * 512 + tid;
            const int r = L >> 3;
            const int c = (L & 7) ^ (r & 7);
            gld_lds16(src + (size_t)(row0 + r) * K + koff + c * 8,
                      (bf16*)(htb + (size_t)L * 16));
        }
    };
    auto STAGE = [&](int t, char* sb) {
        const int ko = t << 6;
        stage_ht(A, bm,       sb,          ko);
        stage_ht(A, bm + 128, sb + HT,     ko);
        stage_ht(Bt, bn,      sb + 2 * HT, ko);
        if (BN_T == 256) stage_ht(Bt, bn + 128, sb + 3 * HT, ko);
    };

    // swizzled fragment reads (plain loads -> compiler-scheduled waits)
    auto rdA = [&](const char* rb, int mf, int kk) -> mfrag {
        const int r  = wm * (MF * 16) + mf * 16 + lrow;
        const int ht = r >> 7, lr = r & 127;
        const int cc = (kk * 4 + lk) ^ (lr & 7);
        return *(const mfrag*)(rb + (size_t)ht * HT + (size_t)lr * 128 + cc * 16);
    };
    auto rdB = [&](const char* rb, int nf, int kk) -> mfrag {
        const int r  = wn * 64 + nf * 16 + lrow;
        const int ht = r >> 7, lr = r & 127;
        const int cc = (kk * 4 + lk) ^ (lr & 7);
        return *(const mfrag*)(rb + (size_t)(2 + ht) * HT + (size_t)lr * 128 + cc * 16);
    };

    f32x4 acc[MF][4];
#pragma unroll
    for (int m = 0; m < MF; ++m)
#pragma unroll
        for (int n = 0; n < 4; ++n) acc[m][n] = f32x4{0.f, 0.f, 0.f, 0.f};

    // prologue
    STAGE(0, smem);
    asm volatile("s_waitcnt vmcnt(0)" ::: "memory");
    __builtin_amdgcn_sched_barrier(0);
    __builtin_amdgcn_s_barrier();

    for (int kt = 0; kt < NT; ++kt) {
        char* rb = smem + (size_t)(kt & 1) * SLOT;
        char* wb = smem + (size_t)((kt + 1) & 1) * SLOT;
        if (kt + 1 < NT) STAGE(kt + 1, wb);   // issue first: ~full K-step of flight

        mfrag bfr[4][2];
#pragma unroll
        for (int nf = 0; nf < 4; ++nf)
#pragma unroll
            for (int kk = 0; kk < 2; ++kk) bfr[nf][kk] = rdB(rb, nf, kk);

#pragma unroll
        for (int h2 = 0; h2 < 2; ++h2) {      // two A-halves to cap register liveness
            mfrag af[MF / 2][2];
#pragma unroll
            for (int mf = 0; mf < MF / 2; ++mf)
#pragma unroll
                for (int kk = 0; kk < 2; ++kk) af[mf][kk] = rdA(rb, h2 * (MF / 2) + mf, kk);
            __builtin_amdgcn_s_setprio(1);
#pragma unroll
            for (int mf = 0; mf < MF / 2; ++mf)
#pragma unroll
                for (int nf = 0; nf < 4; ++nf) {
                    const int mi = h2 * (MF / 2) + mf;
                    acc[mi][nf] = __builtin_amdgcn_mfma_f32_16x16x32_bf16(af[mf][0], bfr[nf][0], acc[mi][nf], 0, 0, 0);
                    acc[mi][nf] = __builtin_amdgcn_mfma_f32_16x16x32_bf16(af[mf][1], bfr[nf][1], acc[mi][nf], 0, 0, 0);
                }
            __builtin_amdgcn_s_setprio(0);
        }

        if (kt + 1 < NT) {
            asm volatile("s_waitcnt vmcnt(0)" ::: "memory");  // next buffer landed (long flight)
            __builtin_amdgcn_sched_barrier(0);
            __builtin_amdgcn_s_barrier();                     // swap point (reads all consumed)
            __builtin_amdgcn_sched_barrier(0);
        }
    }

    // epilogue
#pragma unroll
    for (int m = 0; m < MF; ++m)
#pragma unroll
        for (int j2 = 0; j2 < 4; ++j2) {
            const int r = bm + wm * (MF * 16) + m * 16 + lk * 4 + j2;
#pragma unroll
            for (int n = 0; n < 4; ++n) {
                const int c = bn + wn * 64 + n * 16 + lrow;
                if (obf) ((bf16*)Cv)[(size_t)r * N + c] = __float2bfloat16(acc[m][n][j2]);
                else     ((float*)Cv)[(size_t)r * N + c] = acc[m][n][j2];
            }
        }
}

// ---------------------------------------------------------------- fused weight build
__global__ void k_prep_w(const float* __restrict__ Wq, const float* __restrict__ Wk,
                         const float* __restrict__ Wv, const float* __restrict__ Wg,
                         bf16* __restrict__ Wt) {
    __shared__ float t[32][33];
    const int n0 = blockIdx.x * 32;
    const int k0 = blockIdx.y * 32;
    const int tx = threadIdx.x, ty = threadIdx.y;
    const float* src; int cb, cs;
    if (n0 < 1536)      { int m = n0;        src = Wq; cb = (m >> 8) * 512 + (m & 255) * 2; cs = 2; }
    else if (n0 < 3072) { int m = n0 - 1536; src = Wk; cb = (m >> 8) * 512 + (m & 255) * 2; cs = 2; }
    else if (n0 < 6144) { int m = n0 - 3072; src = Wv; cb = m; cs = 1; }
    else                { int m = n0 - 6144; src = Wg; cb = m; cs = 1; }
#pragma unroll
    for (int i = 0; i < 4; ++i) {
        int k = k0 + ty + i * 8;
        t[ty + i * 8][tx] = src[(size_t)k * VD + cb + cs * tx];
    }
    __syncthreads();
#pragma unroll
    for (int i = 0; i < 4; ++i) {
        int n = n0 + ty + i * 8;
        Wt[(size_t)n * HID + k0 + tx] = __float2bfloat16(t[tx][ty + i * 8]);
    }
}

// ---------------------------------------------------------------- transpose+cast
__global__ void k_tr_cast(const float* __restrict__ src, bf16* __restrict__ dst, int R, int Ccol) {
    __shared__ float t[32][33];
    const int c0 = blockIdx.x * 32, r0 = blockIdx.y * 32;
    const int tx = threadIdx.x, ty = threadIdx.y;
#pragma unroll
    for (int i = 0; i < 4; ++i)
        t[ty + i * 8][tx] = src[(size_t)(r0 + ty + i * 8) * Ccol + c0 + tx];
    __syncthreads();
#pragma unroll
    for (int i = 0; i < 4; ++i)
        dst[(size_t)(c0 + ty + i * 8) * R + r0 + tx] = __float2bfloat16(t[tx][ty + i * 8]);
}

// ---------------------------------------------------------------- alpha/beta + hs->bf16 cast (fused)
__global__ __launch_bounds__(256) void k_ab(const float* __restrict__ hs, const float* __restrict__ Wa,
                                            const float* __restrict__ Wb,
                                            float* __restrict__ alpha, float* __restrict__ beta,
                                            bf16* __restrict__ hsb) {
    const int tok = blockIdx.x;
    const int tid = threadIdx.x;
    float part[12];
#pragma unroll
    for (int j = 0; j < 12; ++j) part[j] = 0.f;
    const float* hrow = hs + (size_t)tok * HID;
    bf16* hbrow = hsb + (size_t)tok * HID;
    for (int i = 0; i < 8; ++i) {
        int k = i * 256 + tid;
        float x = hrow[k];
        hbrow[k] = __float2bfloat16(x);
        const float* wa = Wa + k * NH;
        const float* wb = Wb + k * NH;
#pragma unroll
        for (int j = 0; j < NH; ++j) {
            part[j]     = fmaf(x, wa[j], part[j]);
            part[6 + j] = fmaf(x, wb[j], part[6 + j]);
        }
    }
    __shared__ float red[12][4];
    const int lane = tid & 63, wv = tid >> 6;
#pragma unroll
    for (int j = 0; j < 12; ++j) {
        float s = part[j];
        for (int off = 32; off; off >>= 1) s += __shfl_down(s, off);
        if (lane == 0) red[j][wv] = s;
    }
    __syncthreads();
    if (tid < 12) {
        float s = red[tid][0] + red[tid][1] + red[tid][2] + red[tid][3];
        float v = 1.f / (1.f + expf(-s));
        if (tid < 6) alpha[(size_t)tok * NH + tid] = v;
        else         beta [(size_t)tok * NH + tid - 6] = v;
    }
}

// ---------------------------------------------------------------- conv + phase + rotate + local chunk scan
__global__ __launch_bounds__(256) void k_scan1(const bf16* __restrict__ X,
                                               const float* __restrict__ alpha,
                                               const float* __restrict__ beta,
                                               const float* __restrict__ cq,
                                               const float* __restrict__ ck,
                                               const float* __restrict__ cv,
                                               float* __restrict__ U, float* __restrict__ pp) {
    const int bx = blockIdx.x;
    const int c  = bx % NC;
    const int h  = (bx / NC) % NH;
    const int b  = bx / (NC * NH);
    const int p  = threadIdx.x;
    const int t0 = c * CHUNK;
    const int ch2 = h * HD + 2 * p;
    const float wq0 = cq[ch2 * 4 + 0], wq1 = cq[ch2 * 4 + 1], wq2 = cq[ch2 * 4 + 2], wq3 = cq[ch2 * 4 + 3];
    const float wk0 = ck[ch2 * 4 + 0], wk1 = ck[ch2 * 4 + 1], wk2 = ck[ch2 * 4 + 2], wk3 = ck[ch2 * 4 + 3];
    const float wa0 = cv[ch2 * 4 + 0], wa1 = cv[ch2 * 4 + 1], wa2 = cv[ch2 * 4 + 2], wa3 = cv[ch2 * 4 + 3];
    const float wb0 = cv[(ch2 + 1) * 4 + 0], wb1 = cv[(ch2 + 1) * 4 + 1],
                wb2 = cv[(ch2 + 1) * 4 + 2], wb3 = cv[(ch2 + 1) * 4 + 3];
    const float invf = exp2f(-13.287712379549449f * ((float)p * (1.0f / 256.0f)));
    const int qcol = h * NPAIR + p;
    const int kcol = 1536 + h * NPAIR + p;
    const int vcol = 3072 + ch2;

    float xq[3], xk[3], xv0[3], xv1[3];
#pragma unroll
    for (int i = 0; i < 3; ++i) {
        int t = t0 - 3 + i;
        if (t >= 0) {
            size_t tok = (size_t)b * 2048 + t;
            const bf16* xr = X + tok * N1;
            xq[i] = __bfloat162float(xr[qcol]);
            xk[i] = __bfloat162float(xr[kcol]);
            __hip_bfloat162 vv = *(const __hip_bfloat162*)&xr[vcol];
            xv0[i] = __bfloat162float(vv.x);
            xv1[i] = __bfloat162float(vv.y);
        } else { xq[i] = xk[i] = xv0[i] = xv1[i] = 0.f; }
    }

    float u0 = 0.f, u1 = 0.f, ap = 1.f;
    for (int t = t0; t < t0 + CHUNK; ++t) {
        const size_t tok = (size_t)b * 2048 + t;
        const bf16* xr = X + tok * N1;
        float nq = __bfloat162float(xr[qcol]);
        float nk = __bfloat162float(xr[kcol]);
        __hip_bfloat162 vv = *(const __hip_bfloat162*)&xr[vcol];
        float nv0 = __bfloat162float(vv.x);
        float nv1 = __bfloat162float(vv.y);
        float yq  = wq3 * nq  + wq2 * xq[2]  + wq1 * xq[1]  + wq0 * xq[0];
        float yk  = wk3 * nk  + wk2 * xk[2]  + wk1 * xk[1]  + wk0 * xk[0];
        float yv0 = wa3 * nv0 + wa2 * xv0[2] + wa1 * xv0[1] + wa0 * xv0[0];
        float yv1 = wb3 * nv1 + wb2 * xv1[2] + wb1 * xv1[1] + wb0 * xv1[0];
        xq[0] = xq[1]; xq[1] = xq[2]; xq[2] = nq;
        xk[0] = xk[1]; xk[1] = xk[2]; xk[2] = nk;
        xv0[0] = xv0[1]; xv0[1] = xv0[2]; xv0[2] = nv0;
        xv1[0] = xv1[1]; xv1[1] = xv1[2]; xv1[2] = nv1;
        float theta = yq * invf, psi = yk * invf;
        float d = psi - theta, sn, cs;
        __sincosf(d, &sn, &cs);
        float w0 = yv0 * cs - yv1 * sn;
        float w1 = yv1 * cs + yv0 * sn;
        float a  = alpha[tok * NH + h];
        float bb = beta [tok * NH + h];
        u0 = fmaf(a, u0, bb * w0);
        u1 = fmaf(a, u1, bb * w1);
        ap *= a;
        *(float2*)&U[tok * (size_t)VD + h * HD + 2 * p] = float2{u0, u1};
        if (p == 0) pp[tok * NH + h] = ap;
    }
}

// ---------------------------------------------------------------- cross-chunk carry (prefetched recurrence)
__global__ __launch_bounds__(512) void k_carry(const float* __restrict__ U, const float* __restrict__ pp,
                                               float* __restrict__ carry) {
    const int bh = blockIdx.x;              // 0..11 = b*NH+h
    const int b = bh / NH, h = bh % NH;
    const int d = threadIdx.x;              // 0..511
    float ue[NC], pv[NC];
#pragma unroll
    for (int c = 0; c < NC; ++c) {          // independent loads: all in flight
        size_t tok = (size_t)b * 2048 + c * CHUNK + CHUNK - 1;
        ue[c] = U[tok * (size_t)VD + h * HD + d];
        pv[c] = pp[tok * NH + h];
    }
    float s = 0.f;
#pragma unroll
    for (int c = 0; c < NC; ++c) {
        carry[((size_t)bh * NC + c) * HD + d] = s;
        s = ue[c] + pv[c] * s;
    }
}

// ---------------------------------------------------------------- carry fix + RMS + SiLU gate -> bf16 O
__global__ __launch_bounds__(256) void k_pass3(const float* __restrict__ U, const float* __restrict__ pp,
                                               const float* __restrict__ carry, const bf16* __restrict__ X,
                                               const float* __restrict__ rms_w, bf16* __restrict__ O) {
    const int bx = blockIdx.x;
    const int h = bx % NH;
    const size_t tok = bx / NH;
    const int b = (int)(tok >> 11);
    const int t = (int)(tok & 2047);
    const int c = t / CHUNK;
    const int tid = threadIdx.x;
    const int d = tid * 2;
    float2 uu = *(const float2*)&U[tok * (size_t)VD + h * HD + d];
    float  P  = pp[tok * NH + h];
    float2 cy = *(const float2*)&carry[((size_t)(b * NH + h) * NC + c) * HD + d];
    float u0 = fmaf(P, cy.x, uu.x);
    float u1 = fmaf(P, cy.y, uu.y);
    float s = u0 * u0 + u1 * u1;
    for (int off = 32; off; off >>= 1) s += __shfl_down(s, off);
    __shared__ float r4[4];
    const int lane = tid & 63, wv = tid >> 6;
    if (lane == 0) r4[wv] = s;
    __syncthreads();
    float tot = r4[0] + r4[1] + r4[2] + r4[3];
    float rms = rsqrtf(tot * (1.f / 512.f) + 1e-5f);
    __hip_bfloat162 gg = *(const __hip_bfloat162*)&X[tok * N1 + 6144 + h * HD + d];
    float g0 = __bfloat162float(gg.x), g1 = __bfloat162float(gg.y);
    float si0 = g0 / (1.f + expf(-g0));
    float si1 = g1 / (1.f + expf(-g1));
    float o0 = u0 * rms * rms_w[d]     * si0;
    float o1 = u1 * rms * rms_w[d + 1] * si1;
    __hip_bfloat162 ob;
    ob.x = __float2bfloat16(o0);
    ob.y = __float2bfloat16(o1);
    *(__hip_bfloat162*)&O[tok * (size_t)VD + h * HD + d] = ob;
}

// ----------------------------------------------------------------
extern "C" void kernel_launch(void* const* d_in, const int* in_sizes, int n_in,
                              void* d_out, int out_size, void* d_ws, size_t ws_size,
                              hipStream_t stream) {
    const float* hs   = (const float*)d_in[0];
    const float* Wq   = (const float*)d_in[1];
    const float* Wk   = (const float*)d_in[2];
    const float* Wv   = (const float*)d_in[3];
    const float* Wa   = (const float*)d_in[4];
    const float* Wb   = (const float*)d_in[5];
    const float* Wg   = (const float*)d_in[6];
    const float* Wo   = (const float*)d_in[7];
    const float* cq   = (const float*)d_in[8];
    const float* ck   = (const float*)d_in[9];
    const float* cv   = (const float*)d_in[10];
    const float* rmsw = (const float*)d_in[11];

    char* ws = (char*)d_ws;
    size_t off = 0;
    auto alloc = [&](size_t bytes) -> void* {
        void* p = ws + off;
        off = (off + bytes + 255) & ~(size_t)255;
        return p;
    };
    bf16*  hsb   = (bf16*) alloc((size_t)TOKENS * HID * 2);
    bf16*  Wt    = (bf16*) alloc((size_t)N1 * HID * 2);
    bf16*  Wot   = (bf16*) alloc((size_t)HID * VD * 2);
    bf16*  X     = (bf16*) alloc((size_t)TOKENS * N1 * 2);
    float* U     = (float*)alloc((size_t)TOKENS * VD * 4);
    float* alp   = (float*)alloc((size_t)TOKENS * NH * 4);
    float* bet   = (float*)alloc((size_t)TOKENS * NH * 4);
    float* pp    = (float*)alloc((size_t)TOKENS * NH * 4);
    float* carry = (float*)alloc((size_t)2 * NH * NC * HD * 4);
    bf16*  O     = (bf16*)Wt;   // alias: Wt dead after GEMM-1

    hipFuncSetAttribute((const void*)k_gemm2<256>,
                        hipFuncAttributeMaxDynamicSharedMemorySize, 2 * 4 * 16384);
    hipFuncSetAttribute((const void*)k_gemm2<128>,
                        hipFuncAttributeMaxDynamicSharedMemorySize, 2 * 3 * 16384);

    k_prep_w<<<dim3(N1 / 32, HID / 32), dim3(32, 8), 0, stream>>>(Wq, Wk, Wv, Wg, Wt);
    k_tr_cast<<<dim3(HID / 32, VD / 32), dim3(32, 8), 0, stream>>>(Wo, Wot, VD, HID);
    k_ab<<<TOKENS, 256, 0, stream>>>(hs, Wa, Wb, alp, bet, hsb);
    // X = hsb @ Wt^T   (M=4096, N=9216, K=2048) -> 16*36 = 576 blocks
    k_gemm2<256><<<dim3((TOKENS / 256) * (N1 / 256)), 512, 2 * 4 * 16384, stream>>>(hsb, Wt, X, TOKENS, N1, HID, 1);
    k_scan1<<<2 * NH * NC, 256, 0, stream>>>(X, alp, bet, cq, ck, cv, U, pp);
    k_carry<<<2 * NH, 512, 0, stream>>>(U, pp, carry);
    k_pass3<<<TOKENS * NH, 256, 0, stream>>>(U, pp, carry, X, rmsw, O);
    // out = O @ Wot^T  (M=4096, N=2048, K=3072) -> 16*16 = 256 blocks
    k_gemm2<128><<<dim3((TOKENS / 256) * (HID / 128)), 512, 2 * 3 * 16384, stream>>>(O, Wot, d_out, TOKENS, HID, VD, 0);
}